// Round 3
// baseline (503.172 us; speedup 1.0000x reference)
//
#include <hip/hip_runtime.h>

typedef unsigned short u16;
typedef unsigned int u32;
typedef __bf16 bf16x8 __attribute__((ext_vector_type(8)));
typedef float f32x4 __attribute__((ext_vector_type(4)));

__device__ __forceinline__ u16 f2b(float f) {
  u32 u = __float_as_uint(f);
  u32 r = (u + 0x7fffu + ((u >> 16) & 1u)) >> 16;   // RNE, inputs finite
  return (u16)r;
}
__device__ __forceinline__ float b2f(u16 h) {
  return __uint_as_float(((u32)h) << 16);
}
__device__ __forceinline__ bf16x8 zero8() {
  union { uint4 u; bf16x8 v; } z; z.u = make_uint4(0u, 0u, 0u, 0u); return z.v;
}
__device__ __forceinline__ u32 cvtpk(float lo, float hi) {
  u32 r;
  asm("v_cvt_pk_bf16_f32 %0, %1, %2" : "=v"(r) : "v"(lo), "v"(hi));
  return r;
}

// ---------------- fused fp32 -> bf16 weight conversions ----------------
struct Seg { const float* in; u16* out; int n4; };
struct Segs { Seg s[9]; };

__global__ __launch_bounds__(256)
void f2b_multi_kernel(Segs segs) {
  const Seg sg = segs.s[blockIdx.y];
  const int i = blockIdx.x * 256 + threadIdx.x;
  if (i < sg.n4) {
    const float4 f = *(const float4*)(sg.in + (size_t)i * 4);
    uint2 pk;
    pk.x = (u32)f2b(f.x) | ((u32)f2b(f.y) << 16);
    pk.y = (u32)f2b(f.z) | ((u32)f2b(f.w) << 16);
    *(uint2*)(sg.out + (size_t)i * 4) = pk;
  }
}

__global__ void copy_bias_kernel(const float* __restrict__ a, const float* __restrict__ b,
                                 float* __restrict__ out) {
  int i = threadIdx.x;   // 512 threads
  out[i] = (i < 256) ? a[i] : b[i - 256];
}

// ---------------- bias transpose: bias[b][100 q][5440 m] f32 -> biasT[b][m][112 q] bf16
__global__ __launch_bounds__(256)
void bias_tr_kernel(const float* __restrict__ bias, u16* __restrict__ biasT)
{
  __shared__ float S[100][69];
  const int tid = threadIdx.x;
  const int m0 = blockIdx.x * 64, b = blockIdx.y;
  for (int idx = tid; idx < 1600; idx += 256) {
    const int q = idx >> 4, seg = idx & 15;
    const float4 v = *(const float4*)(bias + (size_t)(b * 100 + q) * 5440 + m0 + seg * 4);
    S[q][seg * 4 + 0] = v.x; S[q][seg * 4 + 1] = v.y;
    S[q][seg * 4 + 2] = v.z; S[q][seg * 4 + 3] = v.w;
  }
  __syncthreads();
  for (int idx = tid; idx < 1792; idx += 256) {
    const int m = idx / 28, qg = (idx % 28) * 4;
    u16 h[4];
#pragma unroll
    for (int r = 0; r < 4; ++r) {
      const int q = qg + r;
      h[r] = (q < 100) ? f2b(S[q][m]) : (u16)0;
    }
    uint2 pk;
    pk.x = (u32)h[0] | ((u32)h[1] << 16);
    pk.y = (u32)h[2] | ((u32)h[3] << 16);
    *(uint2*)(biasT + ((size_t)(b * 5440 + m0 + m)) * 112 + qg) = pk;
  }
}

// ---------------- LayerNorm (D=256), one wave per row, 4 rows/block -------------
__global__ __launch_bounds__(256)
void ln_kernel(const float* __restrict__ x, const float* __restrict__ w, const float* __restrict__ b,
               const float* __restrict__ pos, u16* __restrict__ outz, u16* __restrict__ outzq)
{
  const int lane = threadIdx.x & 63;
  const int row = blockIdx.x * 4 + (threadIdx.x >> 6);
  const size_t o = (size_t)row * 256 + lane * 4;
  const float4 v = *(const float4*)(x + o);
  float s = v.x + v.y + v.z + v.w;
#pragma unroll
  for (int m = 1; m < 64; m <<= 1) s += __shfl_xor(s, m);
  const float mean = s * (1.f / 256.f);
  const float d0 = v.x - mean, d1 = v.y - mean, d2 = v.z - mean, d3 = v.w - mean;
  float ss = d0 * d0 + d1 * d1 + d2 * d2 + d3 * d3;
#pragma unroll
  for (int m = 1; m < 64; m <<= 1) ss += __shfl_xor(ss, m);
  const float rs = rsqrtf(ss * (1.f / 256.f) + 1e-5f);
  const float4 wv = *(const float4*)(w + lane * 4);
  const float4 bv = *(const float4*)(b + lane * 4);
  float y0 = d0 * rs * wv.x + bv.x;
  float y1 = d1 * rs * wv.y + bv.y;
  float y2 = d2 * rs * wv.z + bv.z;
  float y3 = d3 * rs * wv.w + bv.w;
  if (outz) {
    uint2 pk;
    pk.x = (u32)f2b(y0) | ((u32)f2b(y1) << 16);
    pk.y = (u32)f2b(y2) | ((u32)f2b(y3) << 16);
    *(uint2*)(outz + o) = pk;
  }
  if (outzq) {
    const float4 pv = *(const float4*)(pos + o);
    uint2 pk;
    pk.x = (u32)f2b(y0 + pv.x) | ((u32)f2b(y1 + pv.y) << 16);
    pk.y = (u32)f2b(y2 + pv.z) | ((u32)f2b(y3 + pv.w) << 16);
    *(uint2*)(outzq + o) = pk;
  }
}

// ---------------- Generic GEMM: C[M,N] = A[M,K] @ W[N,K]^T + bias -------------
template<int BM, int BN, int WM, int WN, int AF32, int GELU_, int RES_, int OF32, int OBF>
__global__ __launch_bounds__(256)
void gemm_kernel(const void* __restrict__ Ap, const u16* __restrict__ W,
                 const float* __restrict__ bias, const float* __restrict__ res,
                 float* __restrict__ Cf, u16* __restrict__ Cb,
                 int M, int N, int K, float scale)
{
  constexpr int WROWS = BM / WM;
  constexpr int WCOLS = BN / WN;
  constexpr int MT = WROWS / 16;
  constexpr int NT = WCOLS / 16;
  static_assert(WM * WN == 4, "4 waves");
  __shared__ u16 As[BM][40];
  __shared__ u16 Ws[BN][40];
  const int tid = threadIdx.x, lane = tid & 63, wid = tid >> 6;
  const int g = lane >> 4, lr = lane & 15;
  const int m0 = blockIdx.x * BM, n0 = blockIdx.y * BN;
  const int wm = wid / WN, wn = wid % WN;
  f32x4 acc[MT][NT] = {};
  for (int k0 = 0; k0 < K; k0 += 32) {
    for (int cid = tid; cid < BM * 4; cid += 256) {
      int r = cid >> 2, cg = (cid & 3) * 8;
      if constexpr (AF32) {
        const float* ap = (const float*)Ap + (size_t)(m0 + r) * K + k0 + cg;
        float4 f0 = *(const float4*)ap;
        float4 f1 = *(const float4*)(ap + 4);
        uint4 pk;
        pk.x = (u32)f2b(f0.x) | ((u32)f2b(f0.y) << 16);
        pk.y = (u32)f2b(f0.z) | ((u32)f2b(f0.w) << 16);
        pk.z = (u32)f2b(f1.x) | ((u32)f2b(f1.y) << 16);
        pk.w = (u32)f2b(f1.z) | ((u32)f2b(f1.w) << 16);
        *(uint4*)&As[r][cg] = pk;
      } else {
        *(uint4*)&As[r][cg] = *(const uint4*)((const u16*)Ap + (size_t)(m0 + r) * K + k0 + cg);
      }
    }
    for (int cid = tid; cid < BN * 4; cid += 256) {
      int r = cid >> 2, cg = (cid & 3) * 8;
      *(uint4*)&Ws[r][cg] = *(const uint4*)(W + (size_t)(n0 + r) * K + k0 + cg);
    }
    __syncthreads();
    bf16x8 af[MT], bfr[NT];
#pragma unroll
    for (int mt = 0; mt < MT; ++mt) af[mt] = *(const bf16x8*)&As[wm * WROWS + mt * 16 + lr][g * 8];
#pragma unroll
    for (int nt = 0; nt < NT; ++nt) bfr[nt] = *(const bf16x8*)&Ws[wn * WCOLS + nt * 16 + lr][g * 8];
#pragma unroll
    for (int mt = 0; mt < MT; ++mt)
#pragma unroll
      for (int nt = 0; nt < NT; ++nt)
        acc[mt][nt] = __builtin_amdgcn_mfma_f32_16x16x32_bf16(af[mt], bfr[nt], acc[mt][nt], 0, 0, 0);
    __syncthreads();
  }
#pragma unroll
  for (int mt = 0; mt < MT; ++mt)
#pragma unroll
    for (int nt = 0; nt < NT; ++nt) {
      const int col = n0 + wn * WCOLS + nt * 16 + lr;
      const float bv = bias[col];
#pragma unroll
      for (int r = 0; r < 4; ++r) {
        const int row = m0 + wm * WROWS + mt * 16 + g * 4 + r;
        float v = (acc[mt][nt][r] + bv) * scale;
        if constexpr (GELU_) v = 0.5f * v * (1.f + erff(v * 0.70710678118654752f));
        if constexpr (RES_) v += res[(size_t)row * N + col];
        if constexpr (OF32) Cf[(size_t)row * N + col] = v;
        if constexpr (OBF) Cb[(size_t)row * N + col] = f2b(v);
      }
    }
}

// ---------------- KV projection GEMM — LDS-free direct-fragment version -------
// A = memory fp32 [87040,256].  Grid: x = 16 b * 43 m-tiles (BM=128), y = 0..3
// (y<2: K output cols y*128; y>=2: V output cols (y-2)*128).
// 4 waves 2x2; wave tile 64x64; fragments loaded straight from global
// (A: 2x dwordx4 fp32 + v_cvt_pk_bf16_f32; W: 1x dwordx4 bf16), K fully unrolled.
// K -> Kb[87040][256] natural; V -> Vt[(b*8+h)*32+d][5440] with 32-block
// permutation p(ml) = 8*((ml&15)>>2) + 2*(ml&3) + (ml>>4)  (matches P32 packing).
__global__ __launch_bounds__(256)
void kv_gemm_kernel(const float* __restrict__ A, const u16* __restrict__ Wk,
                    const u16* __restrict__ Wv, const float* __restrict__ biasKV,
                    u16* __restrict__ Kb, u16* __restrict__ Vt)
{
  const int tid = threadIdx.x, lane = tid & 63, wid = tid >> 6;
  const int g = lane >> 4, lr = lane & 15;
  const int bidx = blockIdx.x / 43, t = blockIdx.x - bidx * 43;
  const int isV = (int)(blockIdx.y >> 1);
  const u16* W = isV ? Wv : Wk;
  const int n0 = (blockIdx.y & 1) * 128 + (wid & 1) * 64;       // col base of wave
  const int mloc0 = t * 128 + (wid >> 1) * 64;                  // local row base of wave

  // per-fragment global bases
  const float* Ab[4];
  const u16* Wb[4];
#pragma unroll
  for (int mt = 0; mt < 4; ++mt) {
    int rl = mloc0 + mt * 16 + lr;
    int ar = bidx * 5440 + (rl < 5440 ? rl : 5439);             // clamp tail tile
    Ab[mt] = A + (size_t)ar * 256 + g * 8;
  }
#pragma unroll
  for (int nt = 0; nt < 4; ++nt)
    Wb[nt] = W + (size_t)(n0 + nt * 16 + lr) * 256 + g * 8;

  f32x4 acc[4][4] = {};
#pragma unroll
  for (int ks = 0; ks < 8; ++ks) {
    bf16x8 af[4], bfv[4];
#pragma unroll
    for (int nt = 0; nt < 4; ++nt)
      bfv[nt] = *(const bf16x8*)(Wb[nt] + ks * 32);
#pragma unroll
    for (int mt = 0; mt < 4; ++mt) {
      const float4 f0 = *(const float4*)(Ab[mt] + ks * 32);
      const float4 f1 = *(const float4*)(Ab[mt] + ks * 32 + 4);
      union { uint4 u; bf16x8 v; } pk;
      pk.u.x = cvtpk(f0.x, f0.y);
      pk.u.y = cvtpk(f0.z, f0.w);
      pk.u.z = cvtpk(f1.x, f1.y);
      pk.u.w = cvtpk(f1.z, f1.w);
      af[mt] = pk.v;
    }
#pragma unroll
    for (int mt = 0; mt < 4; ++mt)
#pragma unroll
      for (int nt = 0; nt < 4; ++nt)
        acc[mt][nt] = __builtin_amdgcn_mfma_f32_16x16x32_bf16(af[mt], bfv[nt], acc[mt][nt], 0, 0, 0);
  }

  if (!isV) {
#pragma unroll
    for (int nt = 0; nt < 4; ++nt) {
      const int col = n0 + nt * 16 + lr;
      const float bv = biasKV[col];
#pragma unroll
      for (int mt = 0; mt < 4; ++mt)
#pragma unroll
        for (int r = 0; r < 4; ++r) {
          const int mloc = mloc0 + mt * 16 + g * 4 + r;
          if (mloc < 5440)
            Kb[(size_t)(bidx * 5440 + mloc) * 256 + col] = f2b(acc[mt][nt][r] + bv);
        }
    }
  } else {
#pragma unroll
    for (int nt = 0; nt < 4; ++nt) {
      const int col = n0 + nt * 16 + lr;                        // d in [0,256)
      const float bv = biasKV[256 + col];
      const size_t rowbase = ((size_t)(bidx * 8 + (col >> 5)) * 32 + (col & 31)) * 5440;
#pragma unroll
      for (int mt = 0; mt < 4; ++mt)
#pragma unroll
        for (int r = 0; r < 4; ++r) {
          const int mloc = mloc0 + mt * 16 + g * 4 + r;
          if (mloc < 5440) {
            const int ml = mloc & 31;
            const int p = 8 * ((ml & 15) >> 2) + 2 * (ml & 3) + (ml >> 4);
            Vt[rowbase + (mloc & ~31) + p] = f2b(acc[mt][nt][r] + bv);
          }
        }
    }
  }
}

// ---------------- Cross-attention, flash split-K over NM ----------------
__global__ __launch_bounds__(256, 3)
void cross_attn_kernel(const u16* __restrict__ Q, const u16* __restrict__ Kb,
                       const u16* __restrict__ Vt, const u16* __restrict__ biasT,
                       float* __restrict__ Opart, float* __restrict__ ML)
{
  __shared__ u32 P32[4][112][20];
  const int tid = threadIdx.x, lane = tid & 63, wid = tid >> 6;
  const int g = lane >> 4, lr = lane & 15;
  const int b = blockIdx.y, c = blockIdx.x;
  const int head = blockIdx.z * 4 + wid;
  const int m_base = c * 320;
  const f32x4 zf = {0.f, 0.f, 0.f, 0.f};

  bf16x8 qf[7];
#pragma unroll
  for (int mt = 0; mt < 7; ++mt) {
    int qr = mt * 16 + lr;
    qf[mt] = (qr < 100) ? *(const bf16x8*)&Q[(size_t)(b * 100 + qr) * 256 + head * 32 + g * 8]
                        : zero8();
  }
  float Mst[7];
  f32x4 Lp[7];
  f32x4 Oa[7][2];
#pragma unroll
  for (int mt = 0; mt < 7; ++mt) { Mst[mt] = -1e30f; Lp[mt] = zf; Oa[mt][0] = zf; Oa[mt][1] = zf; }

  for (int s = 0; s < 10; ++s) {
    const int m0 = m_base + s * 32;
    const bf16x8 kf0 = *(const bf16x8*)&Kb[(size_t)(b * 5440 + m0 + lr) * 256 + head * 32 + g * 8];
    const bf16x8 kf1 = *(const bf16x8*)&Kb[(size_t)(b * 5440 + m0 + 16 + lr) * 256 + head * 32 + g * 8];
    const size_t vrow = ((size_t)(b * 8 + head) * 32 + lr) * 5440 + m0 + g * 8;
    const bf16x8 vf0 = *(const bf16x8*)&Vt[vrow];
    const bf16x8 vf1 = *(const bf16x8*)&Vt[vrow + 16 * 5440];
    const u16* bb = biasT + ((size_t)(b * 5440 + m0 + lr)) * 112 + g * 4;
#pragma unroll
    for (int mt = 0; mt < 7; ++mt) {
      f32x4 s0 = __builtin_amdgcn_mfma_f32_16x16x32_bf16(qf[mt], kf0, zf, 0, 0, 0);
      f32x4 s1 = __builtin_amdgcn_mfma_f32_16x16x32_bf16(qf[mt], kf1, zf, 0, 0, 0);
      const uint2 b0 = *(const uint2*)(bb + mt * 16);
      const uint2 b1 = *(const uint2*)(bb + 16 * 112 + mt * 16);
      s0[0] += b2f((u16)b0.x);      s0[1] += b2f((u16)(b0.x >> 16));
      s0[2] += b2f((u16)b0.y);      s0[3] += b2f((u16)(b0.y >> 16));
      s1[0] += b2f((u16)b1.x);      s1[1] += b2f((u16)(b1.x >> 16));
      s1[2] += b2f((u16)b1.y);      s1[3] += b2f((u16)(b1.y >> 16));
      float mx = fmaxf(fmaxf(fmaxf(s0[0], s0[1]), fmaxf(s0[2], s0[3])),
                       fmaxf(fmaxf(s1[0], s1[1]), fmaxf(s1[2], s1[3])));
#pragma unroll
      for (int d = 1; d < 16; d <<= 1) mx = fmaxf(mx, __shfl_xor(mx, d, 16));
      const float newM = fmaxf(Mst[mt], mx);
      const float al = __expf(Mst[mt] - newM);
      Mst[mt] = newM;
      f32x4 p0, p1;
#pragma unroll
      for (int r = 0; r < 4; ++r) {
        p0[r] = __expf(s0[r] - newM);
        p1[r] = __expf(s1[r] - newM);
      }
      Lp[mt] = Lp[mt] * al + (p0 + p1);
      Oa[mt][0] *= al;
      Oa[mt][1] *= al;
#pragma unroll
      for (int r = 0; r < 4; ++r)
        P32[wid][mt * 16 + g * 4 + r][lr] = (u32)f2b(p0[r]) | ((u32)f2b(p1[r]) << 16);
    }
#pragma unroll
    for (int mt = 0; mt < 7; ++mt) {
      const bf16x8 pa = *(const bf16x8*)&P32[wid][mt * 16 + lr][g * 4];
      Oa[mt][0] = __builtin_amdgcn_mfma_f32_16x16x32_bf16(pa, vf0, Oa[mt][0], 0, 0, 0);
      Oa[mt][1] = __builtin_amdgcn_mfma_f32_16x16x32_bf16(pa, vf1, Oa[mt][1], 0, 0, 0);
    }
  }
  const int bh = b * 8 + head;
#pragma unroll
  for (int mt = 0; mt < 7; ++mt)
#pragma unroll
    for (int r = 0; r < 4; ++r) {
      const int qr = mt * 16 + g * 4 + r;
      if (qr < 100) {
        float L = Lp[mt][r];
#pragma unroll
        for (int d = 1; d < 16; d <<= 1) L += __shfl_xor(L, d, 16);
        const size_t rb = (size_t)(bh * 17 + c) * 100 + qr;
        Opart[rb * 32 + lr] = Oa[mt][0][r];
        Opart[rb * 32 + 16 + lr] = Oa[mt][1][r];
        if (lr == 0) { ML[rb * 2] = Mst[mt]; ML[rb * 2 + 1] = L; }
      }
    }
}

// ---------------- Combine cross-attn partials -> attn_out bf16 [1600,256] ------
__global__ __launch_bounds__(256)
void reduce_attn_kernel(const float* __restrict__ Opart, const float* __restrict__ ML,
                        u16* __restrict__ outb)
{
  const int row = blockIdx.x;            // 0..1599
  const int b = row / 100, q = row % 100;
  const int h = threadIdx.x >> 5, d = threadIdx.x & 31;
  const int bh = b * 8 + h;
  float gm = -1e30f;
  for (int c = 0; c < 17; ++c) gm = fmaxf(gm, ML[((size_t)(bh * 17 + c) * 100 + q) * 2]);
  float l = 0.f, o = 0.f;
  for (int c = 0; c < 17; ++c) {
    const size_t rb = (size_t)(bh * 17 + c) * 100 + q;
    const float w = __expf(ML[rb * 2] - gm);
    l += ML[rb * 2 + 1] * w;
    o += Opart[rb * 32 + d] * w;
  }
  outb[(size_t)row * 256 + h * 32 + d] = f2b(o / l);
}

// ---------------- Self-attention (NQ=100, tiny) ----------------
__global__ __launch_bounds__(128)
void self_attn_kernel(const float* __restrict__ qk, const float* __restrict__ vs,
                      u16* __restrict__ so)
{
  __shared__ u16 kk[100][36];
  __shared__ u16 vv[100][36];
  __shared__ float S[100][101];
  const int b = blockIdx.x >> 3, h = blockIdx.x & 7;
  const int t = threadIdx.x;
  for (int e = t; e < 3200; e += 128) {
    const int r = e >> 5, cq = e & 31;
    kk[r][cq] = f2b(qk[(size_t)(b * 100 + r) * 512 + 256 + h * 32 + cq]);
    vv[r][cq] = f2b(vs[(size_t)(b * 100 + r) * 256 + h * 32 + cq]);
  }
  __syncthreads();
  if (t < 100) {
    float qr_[32];
#pragma unroll
    for (int cq = 0; cq < 32; ++cq) qr_[cq] = qk[(size_t)(b * 100 + t) * 512 + h * 32 + cq];
    for (int m = 0; m < 100; ++m) {
      float dp = 0.f;
#pragma unroll
      for (int cq = 0; cq < 32; ++cq) dp += qr_[cq] * b2f(kk[m][cq]);
      S[t][m] = dp * 0.17677669529663687f;
    }
    float mx = -1e30f;
    for (int m = 0; m < 100; ++m) mx = fmaxf(mx, S[t][m]);
    float sum = 0.f;
    for (int m = 0; m < 100; ++m) { const float p = __expf(S[t][m] - mx); S[t][m] = p; sum += p; }
    const float inv = 1.f / sum;
    float o[32];
#pragma unroll
    for (int cq = 0; cq < 32; ++cq) o[cq] = 0.f;
    for (int m = 0; m < 100; ++m) {
      const float p = S[t][m];
#pragma unroll
      for (int cq = 0; cq < 32; ++cq) o[cq] += p * b2f(vv[m][cq]);
    }
#pragma unroll
    for (int cq = 0; cq < 32; ++cq)
      so[(size_t)(b * 100 + t) * 256 + h * 32 + cq] = f2b(o[cq] * inv);
  }
}

// ---------------- mask_logits: per-b [100,256] @ hr[b][4096,256]^T (hr fp32 inline-cvt)
__global__ __launch_bounds__(256)
void mask_gemm_kernel(const u16* __restrict__ tm, const float* __restrict__ hr,
                      float* __restrict__ out)
{
  __shared__ u16 As[112][40];
  __shared__ u16 Bs[64][40];
  const int tid = threadIdx.x, lane = tid & 63, wid = tid >> 6;
  const int g = lane >> 4, lr = lane & 15;
  const int b = blockIdx.y, n0 = blockIdx.x * 64;
  f32x4 acc[7] = {};
  for (int k0 = 0; k0 < 256; k0 += 32) {
    for (int cid = tid; cid < 448; cid += 256) {
      const int r = cid >> 2, cg = (cid & 3) * 8;
      uint4 val = {0u, 0u, 0u, 0u};
      if (r < 100) val = *(const uint4*)&tm[(size_t)(b * 100 + r) * 256 + k0 + cg];
      *(uint4*)&As[r][cg] = val;
    }
    {
      const int r = tid >> 2, cg = (tid & 3) * 8;
      const float* hp = hr + (size_t)(b * 4096 + n0 + r) * 256 + k0 + cg;
      float4 f0 = *(const float4*)hp;
      float4 f1 = *(const float4*)(hp + 4);
      uint4 pk;
      pk.x = (u32)f2b(f0.x) | ((u32)f2b(f0.y) << 16);
      pk.y = (u32)f2b(f0.z) | ((u32)f2b(f0.w) << 16);
      pk.z = (u32)f2b(f1.x) | ((u32)f2b(f1.y) << 16);
      pk.w = (u32)f2b(f1.z) | ((u32)f2b(f1.w) << 16);
      *(uint4*)&Bs[r][cg] = pk;
    }
    __syncthreads();
    const bf16x8 bfr = *(const bf16x8*)&Bs[wid * 16 + lr][g * 8];
#pragma unroll
    for (int mt = 0; mt < 7; ++mt) {
      const bf16x8 af = *(const bf16x8*)&As[mt * 16 + lr][g * 8];
      acc[mt] = __builtin_amdgcn_mfma_f32_16x16x32_bf16(af, bfr, acc[mt], 0, 0, 0);
    }
    __syncthreads();
  }
#pragma unroll
  for (int mt = 0; mt < 7; ++mt)
#pragma unroll
    for (int r = 0; r < 4; ++r) {
      const int qr = mt * 16 + g * 4 + r;
      if (qr < 100)
        out[(size_t)(b * 100 + qr) * 4096 + n0 + wid * 16 + lr] = acc[mt][r];
    }
}

// =======================================================================
extern "C" void kernel_launch(void* const* d_in, const int* in_sizes, int n_in,
                              void* d_out, int out_size, void* d_ws, size_t ws_size,
                              hipStream_t stream)
{
  (void)in_sizes; (void)n_in; (void)out_size; (void)ws_size;
  const float* tgt      = (const float*)d_in[0];
  const float* memory   = (const float*)d_in[1];
  const float* memhr    = (const float*)d_in[2];
  const float* pbias    = (const float*)d_in[3];
  const float* qpos     = (const float*)d_in[4];
  const float* lncw     = (const float*)d_in[5];
  const float* lncb     = (const float*)d_in[6];
  const float* q_w      = (const float*)d_in[7];
  const float* q_b      = (const float*)d_in[8];
  const float* k_w      = (const float*)d_in[9];
  const float* k_b      = (const float*)d_in[10];
  const float* v_w      = (const float*)d_in[11];
  const float* v_b      = (const float*)d_in[12];
  const float* out_w    = (const float*)d_in[13];
  const float* out_b    = (const float*)d_in[14];
  const float* lnsw     = (const float*)d_in[15];
  const float* lnsb     = (const float*)d_in[16];
  const float* sa_in_w  = (const float*)d_in[17];
  const float* sa_in_b  = (const float*)d_in[18];
  const float* sa_out_w = (const float*)d_in[19];
  const float* sa_out_b = (const float*)d_in[20];
  const float* lnfw     = (const float*)d_in[21];
  const float* lnfb     = (const float*)d_in[22];
  const float* l1w      = (const float*)d_in[23];
  const float* l1b      = (const float*)d_in[24];
  const float* l2w      = (const float*)d_in[25];
  const float* l2b      = (const float*)d_in[26];
  const float* me_w     = (const float*)d_in[27];
  const float* me_b     = (const float*)d_in[28];
  float* outf = (float*)d_out;

  char* ws = (char*)d_ws;
  size_t off = 0;
  auto alloc = [&](size_t bytes) -> void* {
    void* p = ws + off;
    off = (off + bytes + 255) & ~(size_t)255;
    return p;
  };
  u16*   kvW   = (u16*)alloc((size_t)131072 * 2);
  u16*   qW    = (u16*)alloc((size_t)65536 * 2);
  u16*   outW  = (u16*)alloc((size_t)65536 * 2);
  u16*   saW   = (u16*)alloc((size_t)196608 * 2);
  u16*   saoW  = (u16*)alloc((size_t)65536 * 2);
  u16*   l1W   = (u16*)alloc((size_t)524288 * 2);
  u16*   l2W   = (u16*)alloc((size_t)524288 * 2);
  u16*   meW   = (u16*)alloc((size_t)65536 * 2);
  float* kvB   = (float*)alloc((size_t)512 * 4);
  u16*   biasT = (u16*)alloc((size_t)9748480 * 2);
  u16*   zq1   = (u16*)alloc((size_t)409600 * 2);
  u16*   Qb    = (u16*)alloc((size_t)409600 * 2);
  u16*   Kb    = (u16*)alloc((size_t)22282240 * 2);
  u16*   Vt    = (u16*)alloc((size_t)22282240 * 2);
  float* Opart = (float*)alloc((size_t)6963200 * 4);
  float* MLp   = (float*)alloc((size_t)435200 * 4);
  u16*   attno = (u16*)alloc((size_t)409600 * 2);
  float* tgt1  = (float*)alloc((size_t)409600 * 4);
  u16*   z2    = (u16*)alloc((size_t)409600 * 2);
  u16*   zq2   = (u16*)alloc((size_t)409600 * 2);
  float* qkb   = (float*)alloc((size_t)819200 * 4);
  float* vsb   = (float*)alloc((size_t)409600 * 4);
  u16*   sob   = (u16*)alloc((size_t)409600 * 2);
  float* tgt2  = (float*)alloc((size_t)409600 * 4);
  u16*   y0b   = (u16*)alloc((size_t)409600 * 2);
  u16*   hb    = (u16*)alloc((size_t)3276800 * 2);
  u16*   t3b   = (u16*)alloc((size_t)409600 * 2);
  u16*   tmb   = (u16*)alloc((size_t)409600 * 2);

  const float SCALE = 0.17677669529663687f;  // 32^-0.5

  // fused weight conversions (one launch) + kv bias pack
  Segs segs;
  segs.s[0] = {k_w,      kvW,          16384};
  segs.s[1] = {v_w,      kvW + 65536,  16384};
  segs.s[2] = {q_w,      qW,           16384};
  segs.s[3] = {out_w,    outW,         16384};
  segs.s[4] = {sa_in_w,  saW,          49152};
  segs.s[5] = {sa_out_w, saoW,         16384};
  segs.s[6] = {l1w,      l1W,          131072};
  segs.s[7] = {l2w,      l2W,          131072};
  segs.s[8] = {me_w,     meW,          16384};
  f2b_multi_kernel<<<dim3(512, 9), 256, 0, stream>>>(segs);
  copy_bias_kernel<<<1, 512, 0, stream>>>(k_b, v_b, kvB);
  bias_tr_kernel<<<dim3(85, 16), 256, 0, stream>>>(pbias, biasT);

  // ---- cross attention ----
  ln_kernel<<<400, 256, 0, stream>>>(tgt, lncw, lncb, qpos, nullptr, zq1);
  gemm_kernel<16, 128, 1, 4, 0, 0, 0, 0, 1><<<dim3(100, 2), 256, 0, stream>>>(
      zq1, qW, q_b, nullptr, nullptr, Qb, 1600, 256, 256, SCALE);
  kv_gemm_kernel<<<dim3(688, 4), 256, 0, stream>>>(memory, kvW, kvW + 65536, kvB, Kb, Vt);
  cross_attn_kernel<<<dim3(17, 16, 2), 256, 0, stream>>>(Qb, Kb, Vt, biasT, Opart, MLp);
  reduce_attn_kernel<<<1600, 256, 0, stream>>>(Opart, MLp, attno);
  gemm_kernel<16, 128, 1, 4, 0, 0, 1, 1, 0><<<dim3(100, 2), 256, 0, stream>>>(
      attno, outW, out_b, tgt, tgt1, nullptr, 1600, 256, 256, 1.f);

  // ---- self attention ----
  ln_kernel<<<400, 256, 0, stream>>>(tgt1, lnsw, lnsb, qpos, z2, zq2);
  gemm_kernel<16, 128, 1, 4, 0, 0, 0, 1, 0><<<dim3(100, 4), 256, 0, stream>>>(
      zq2, saW, sa_in_b, nullptr, qkb, nullptr, 1600, 512, 256, 1.f);
  gemm_kernel<16, 128, 1, 4, 0, 0, 0, 1, 0><<<dim3(100, 2), 256, 0, stream>>>(
      z2, saW + 131072, sa_in_b + 512, nullptr, vsb, nullptr, 1600, 256, 256, 1.f);
  self_attn_kernel<<<128, 128, 0, stream>>>(qkb, vsb, sob);
  gemm_kernel<16, 128, 1, 4, 0, 0, 1, 1, 0><<<dim3(100, 2), 256, 0, stream>>>(
      sob, saoW, sa_out_b, tgt1, tgt2, nullptr, 1600, 256, 256, 1.f);

  // ---- FFN ----
  ln_kernel<<<400, 256, 0, stream>>>(tgt2, lnfw, lnfb, nullptr, y0b, nullptr);
  gemm_kernel<64, 256, 4, 1, 0, 1, 0, 0, 1><<<dim3(25, 8), 256, 0, stream>>>(
      y0b, l1W, l1b, nullptr, nullptr, hb, 1600, 2048, 256, 1.f);
  gemm_kernel<16, 128, 1, 4, 0, 0, 1, 1, 1><<<dim3(100, 2), 256, 0, stream>>>(
      hb, l2W, l2b, tgt2, outf, t3b, 1600, 256, 2048, 1.f);

  // ---- mask branch ----
  gemm_kernel<16, 128, 1, 4, 0, 0, 0, 0, 1><<<dim3(100, 2), 256, 0, stream>>>(
      t3b, meW, me_b, nullptr, nullptr, tmb, 1600, 256, 256, 1.f);
  mask_gemm_kernel<<<dim3(64, 16), 256, 0, stream>>>(tmb, memhr, outf + 409600);
}

// Round 4
// 370.679 us; speedup vs baseline: 1.3574x; 1.3574x over previous
//
#include <hip/hip_runtime.h>

typedef unsigned short u16;
typedef unsigned int u32;
typedef __bf16 bf16x8 __attribute__((ext_vector_type(8)));
typedef float f32x4 __attribute__((ext_vector_type(4)));

__device__ __forceinline__ u16 f2b(float f) {
  u32 u = __float_as_uint(f);
  u32 r = (u + 0x7fffu + ((u >> 16) & 1u)) >> 16;   // RNE, inputs finite
  return (u16)r;
}
__device__ __forceinline__ float b2f(u16 h) {
  return __uint_as_float(((u32)h) << 16);
}
__device__ __forceinline__ bf16x8 zero8() {
  union { uint4 u; bf16x8 v; } z; z.u = make_uint4(0u, 0u, 0u, 0u); return z.v;
}
__device__ __forceinline__ u32 cvtpk(float lo, float hi) {
  u32 r;
  asm("v_cvt_pk_bf16_f32 %0, %1, %2" : "=v"(r) : "v"(lo), "v"(hi));
  return r;
}

// ---------------- fused fp32 -> bf16 weight conversions ----------------
struct Seg { const float* in; u16* out; int n4; };
struct Segs { Seg s[9]; };

__global__ __launch_bounds__(256)
void f2b_multi_kernel(Segs segs) {
  const Seg sg = segs.s[blockIdx.y];
  const int i = blockIdx.x * 256 + threadIdx.x;
  if (i < sg.n4) {
    const float4 f = *(const float4*)(sg.in + (size_t)i * 4);
    uint2 pk;
    pk.x = (u32)f2b(f.x) | ((u32)f2b(f.y) << 16);
    pk.y = (u32)f2b(f.z) | ((u32)f2b(f.w) << 16);
    *(uint2*)(sg.out + (size_t)i * 4) = pk;
  }
}

__global__ void copy_bias_kernel(const float* __restrict__ a, const float* __restrict__ b,
                                 float* __restrict__ out) {
  int i = threadIdx.x;   // 512 threads
  out[i] = (i < 256) ? a[i] : b[i - 256];
}

// ---------------- bias transpose: bias[b][100 q][5440 m] f32 -> biasT[b][m][112 q] bf16
__global__ __launch_bounds__(256)
void bias_tr_kernel(const float* __restrict__ bias, u16* __restrict__ biasT)
{
  __shared__ float S[100][69];
  const int tid = threadIdx.x;
  const int m0 = blockIdx.x * 64, b = blockIdx.y;
  for (int idx = tid; idx < 1600; idx += 256) {
    const int q = idx >> 4, seg = idx & 15;
    const float4 v = *(const float4*)(bias + (size_t)(b * 100 + q) * 5440 + m0 + seg * 4);
    S[q][seg * 4 + 0] = v.x; S[q][seg * 4 + 1] = v.y;
    S[q][seg * 4 + 2] = v.z; S[q][seg * 4 + 3] = v.w;
  }
  __syncthreads();
  for (int idx = tid; idx < 1792; idx += 256) {
    const int m = idx / 28, qg = (idx % 28) * 4;
    u16 h[4];
#pragma unroll
    for (int r = 0; r < 4; ++r) {
      const int q = qg + r;
      h[r] = (q < 100) ? f2b(S[q][m]) : (u16)0;
    }
    uint2 pk;
    pk.x = (u32)h[0] | ((u32)h[1] << 16);
    pk.y = (u32)h[2] | ((u32)h[3] << 16);
    *(uint2*)(biasT + ((size_t)(b * 5440 + m0 + m)) * 112 + qg) = pk;
  }
}

// ---------------- LayerNorm (D=256), one wave per row, 4 rows/block -------------
__global__ __launch_bounds__(256)
void ln_kernel(const float* __restrict__ x, const float* __restrict__ w, const float* __restrict__ b,
               const float* __restrict__ pos, u16* __restrict__ outz, u16* __restrict__ outzq)
{
  const int lane = threadIdx.x & 63;
  const int row = blockIdx.x * 4 + (threadIdx.x >> 6);
  const size_t o = (size_t)row * 256 + lane * 4;
  const float4 v = *(const float4*)(x + o);
  float s = v.x + v.y + v.z + v.w;
#pragma unroll
  for (int m = 1; m < 64; m <<= 1) s += __shfl_xor(s, m);
  const float mean = s * (1.f / 256.f);
  const float d0 = v.x - mean, d1 = v.y - mean, d2 = v.z - mean, d3 = v.w - mean;
  float ss = d0 * d0 + d1 * d1 + d2 * d2 + d3 * d3;
#pragma unroll
  for (int m = 1; m < 64; m <<= 1) ss += __shfl_xor(ss, m);
  const float rs = rsqrtf(ss * (1.f / 256.f) + 1e-5f);
  const float4 wv = *(const float4*)(w + lane * 4);
  const float4 bv = *(const float4*)(b + lane * 4);
  float y0 = d0 * rs * wv.x + bv.x;
  float y1 = d1 * rs * wv.y + bv.y;
  float y2 = d2 * rs * wv.z + bv.z;
  float y3 = d3 * rs * wv.w + bv.w;
  if (outz) {
    uint2 pk;
    pk.x = (u32)f2b(y0) | ((u32)f2b(y1) << 16);
    pk.y = (u32)f2b(y2) | ((u32)f2b(y3) << 16);
    *(uint2*)(outz + o) = pk;
  }
  if (outzq) {
    const float4 pv = *(const float4*)(pos + o);
    uint2 pk;
    pk.x = (u32)f2b(y0 + pv.x) | ((u32)f2b(y1 + pv.y) << 16);
    pk.y = (u32)f2b(y2 + pv.z) | ((u32)f2b(y3 + pv.w) << 16);
    *(uint2*)(outzq + o) = pk;
  }
}

// ---------------- Generic GEMM: C[M,N] = A[M,K] @ W[N,K]^T + bias -------------
template<int BM, int BN, int WM, int WN, int AF32, int GELU_, int RES_, int OF32, int OBF>
__global__ __launch_bounds__(256)
void gemm_kernel(const void* __restrict__ Ap, const u16* __restrict__ W,
                 const float* __restrict__ bias, const float* __restrict__ res,
                 float* __restrict__ Cf, u16* __restrict__ Cb,
                 int M, int N, int K, float scale)
{
  constexpr int WROWS = BM / WM;
  constexpr int WCOLS = BN / WN;
  constexpr int MT = WROWS / 16;
  constexpr int NT = WCOLS / 16;
  static_assert(WM * WN == 4, "4 waves");
  __shared__ u16 As[BM][40];
  __shared__ u16 Ws[BN][40];
  const int tid = threadIdx.x, lane = tid & 63, wid = tid >> 6;
  const int g = lane >> 4, lr = lane & 15;
  const int m0 = blockIdx.x * BM, n0 = blockIdx.y * BN;
  const int wm = wid / WN, wn = wid % WN;
  f32x4 acc[MT][NT] = {};
  for (int k0 = 0; k0 < K; k0 += 32) {
    for (int cid = tid; cid < BM * 4; cid += 256) {
      int r = cid >> 2, cg = (cid & 3) * 8;
      if constexpr (AF32) {
        const float* ap = (const float*)Ap + (size_t)(m0 + r) * K + k0 + cg;
        float4 f0 = *(const float4*)ap;
        float4 f1 = *(const float4*)(ap + 4);
        uint4 pk;
        pk.x = (u32)f2b(f0.x) | ((u32)f2b(f0.y) << 16);
        pk.y = (u32)f2b(f0.z) | ((u32)f2b(f0.w) << 16);
        pk.z = (u32)f2b(f1.x) | ((u32)f2b(f1.y) << 16);
        pk.w = (u32)f2b(f1.z) | ((u32)f2b(f1.w) << 16);
        *(uint4*)&As[r][cg] = pk;
      } else {
        *(uint4*)&As[r][cg] = *(const uint4*)((const u16*)Ap + (size_t)(m0 + r) * K + k0 + cg);
      }
    }
    for (int cid = tid; cid < BN * 4; cid += 256) {
      int r = cid >> 2, cg = (cid & 3) * 8;
      *(uint4*)&Ws[r][cg] = *(const uint4*)(W + (size_t)(n0 + r) * K + k0 + cg);
    }
    __syncthreads();
    bf16x8 af[MT], bfr[NT];
#pragma unroll
    for (int mt = 0; mt < MT; ++mt) af[mt] = *(const bf16x8*)&As[wm * WROWS + mt * 16 + lr][g * 8];
#pragma unroll
    for (int nt = 0; nt < NT; ++nt) bfr[nt] = *(const bf16x8*)&Ws[wn * WCOLS + nt * 16 + lr][g * 8];
#pragma unroll
    for (int mt = 0; mt < MT; ++mt)
#pragma unroll
      for (int nt = 0; nt < NT; ++nt)
        acc[mt][nt] = __builtin_amdgcn_mfma_f32_16x16x32_bf16(af[mt], bfr[nt], acc[mt][nt], 0, 0, 0);
    __syncthreads();
  }
#pragma unroll
  for (int mt = 0; mt < MT; ++mt)
#pragma unroll
    for (int nt = 0; nt < NT; ++nt) {
      const int col = n0 + wn * WCOLS + nt * 16 + lr;
      const float bv = bias[col];
#pragma unroll
      for (int r = 0; r < 4; ++r) {
        const int row = m0 + wm * WROWS + mt * 16 + g * 4 + r;
        float v = (acc[mt][nt][r] + bv) * scale;
        if constexpr (GELU_) v = 0.5f * v * (1.f + erff(v * 0.70710678118654752f));
        if constexpr (RES_) v += res[(size_t)row * N + col];
        if constexpr (OF32) Cf[(size_t)row * N + col] = v;
        if constexpr (OBF) Cb[(size_t)row * N + col] = f2b(v);
      }
    }
}

// ---------------- KV projection GEMM — A-in-LDS-once hybrid ----------------
// C[87040,512] = A[87040,256](f32) @ [k_w;v_w]^T + bias.  1360 blocks x 512 thr.
// Block = 64 rows x 512 cols (K cols 0-255, V cols 256-511) -> A fetched ONCE.
// A staged bf16 in LDS for the FULL K=256 (32 KB, XOR-swizzled, single barrier);
// W fragments loaded direct from global (256 KB, L2-resident, disjoint per wave).
// 8 waves, wave tile 64x64 (MT=4,NT=4): per K-step 4 ds_read + 4 global + 16 MFMA.
// K -> Kb natural; V -> Vt[(b*8+h)*32+d][5440], 32-block permutation
//   p(ml) = 8*((ml&15)>>2) + 2*(ml&3) + (ml>>4)   (matches cross_attn P32 packing).
__global__ __launch_bounds__(512, 4)
void kv_gemm_kernel(const float* __restrict__ A, const u16* __restrict__ Wk,
                    const u16* __restrict__ Wv, const float* __restrict__ biasKV,
                    u16* __restrict__ Kb, u16* __restrict__ Vt)
{
  __shared__ u16 As[64 * 256];
  const int tid = threadIdx.x, lane = tid & 63, wid = tid >> 6;
  const int g = lane >> 4, lr = lane & 15;
  const int bidx = blockIdx.x / 85, t = blockIdx.x - bidx * 85;
  const int row0 = blockIdx.x * 64;            // global row base (85*64 == 5440)

  // ---- stage A tile (64 x 256) fp32 -> bf16, swizzled ----
  for (int ch = tid; ch < 2048; ch += 512) {
    const int r = ch >> 5, c8 = (ch & 31) * 8;
    const float* ap = A + (size_t)(row0 + r) * 256 + c8;
    const float4 f0 = *(const float4*)ap;
    const float4 f1 = *(const float4*)(ap + 4);
    uint4 pk;
    pk.x = cvtpk(f0.x, f0.y);
    pk.y = cvtpk(f0.z, f0.w);
    pk.z = cvtpk(f1.x, f1.y);
    pk.w = cvtpk(f1.z, f1.w);
    const int byte = r * 512 + c8 * 2;
    *(uint4*)((char*)As + (byte ^ ((r & 7) << 4))) = pk;
  }
  __syncthreads();

  // ---- wave setup: wid 0-3 -> K cols wid*64; wid 4-7 -> V cols (wid-4)*64 ----
  const int isV = wid >> 2;
  const u16* W = isV ? Wv : Wk;
  const int n0 = (wid & 3) * 64;
  const u16* Wb[4];
#pragma unroll
  for (int nt = 0; nt < 4; ++nt)
    Wb[nt] = W + (size_t)(n0 + nt * 16 + lr) * 256 + g * 8;

  f32x4 acc[4][4] = {};
#pragma unroll 2
  for (int ks = 0; ks < 8; ++ks) {
    bf16x8 bfv[4], af[4];
#pragma unroll
    for (int nt = 0; nt < 4; ++nt)
      bfv[nt] = *(const bf16x8*)(Wb[nt] + ks * 32);
#pragma unroll
    for (int mt = 0; mt < 4; ++mt) {
      const int r = mt * 16 + lr;
      const int byte = r * 512 + ks * 64 + g * 16;
      af[mt] = *(const bf16x8*)((const char*)As + (byte ^ ((r & 7) << 4)));
    }
#pragma unroll
    for (int mt = 0; mt < 4; ++mt)
#pragma unroll
      for (int nt = 0; nt < 4; ++nt)
        acc[mt][nt] = __builtin_amdgcn_mfma_f32_16x16x32_bf16(af[mt], bfv[nt], acc[mt][nt], 0, 0, 0);
  }

  // ---- epilogue ----
  if (!isV) {
#pragma unroll
    for (int nt = 0; nt < 4; ++nt) {
      const int col = n0 + nt * 16 + lr;
      const float bv = biasKV[col];
#pragma unroll
      for (int mt = 0; mt < 4; ++mt)
#pragma unroll
        for (int r = 0; r < 4; ++r)
          Kb[(size_t)(row0 + mt * 16 + g * 4 + r) * 256 + col] = f2b(acc[mt][nt][r] + bv);
    }
  } else {
    const int mloc0 = t * 64;
#pragma unroll
    for (int nt = 0; nt < 4; ++nt) {
      const int col = n0 + nt * 16 + lr;                        // d in [0,256)
      const float bv = biasKV[256 + col];
      const size_t rowbase = ((size_t)(bidx * 8 + (col >> 5)) * 32 + (col & 31)) * 5440;
#pragma unroll
      for (int mt = 0; mt < 4; ++mt)
#pragma unroll
        for (int r = 0; r < 4; ++r) {
          const int mloc = mloc0 + mt * 16 + g * 4 + r;
          const int ml = mloc & 31;
          const int p = 8 * ((ml & 15) >> 2) + 2 * (ml & 3) + (ml >> 4);
          Vt[rowbase + (mloc & ~31) + p] = f2b(acc[mt][nt][r] + bv);
        }
    }
  }
}

// ---------------- Cross-attention, flash split-K over NM ----------------
__global__ __launch_bounds__(256, 3)
void cross_attn_kernel(const u16* __restrict__ Q, const u16* __restrict__ Kb,
                       const u16* __restrict__ Vt, const u16* __restrict__ biasT,
                       float* __restrict__ Opart, float* __restrict__ ML)
{
  __shared__ u32 P32[4][112][20];
  const int tid = threadIdx.x, lane = tid & 63, wid = tid >> 6;
  const int g = lane >> 4, lr = lane & 15;
  const int b = blockIdx.y, c = blockIdx.x;
  const int head = blockIdx.z * 4 + wid;
  const int m_base = c * 320;
  const f32x4 zf = {0.f, 0.f, 0.f, 0.f};

  bf16x8 qf[7];
#pragma unroll
  for (int mt = 0; mt < 7; ++mt) {
    int qr = mt * 16 + lr;
    qf[mt] = (qr < 100) ? *(const bf16x8*)&Q[(size_t)(b * 100 + qr) * 256 + head * 32 + g * 8]
                        : zero8();
  }
  float Mst[7];
  f32x4 Lp[7];
  f32x4 Oa[7][2];
#pragma unroll
  for (int mt = 0; mt < 7; ++mt) { Mst[mt] = -1e30f; Lp[mt] = zf; Oa[mt][0] = zf; Oa[mt][1] = zf; }

  for (int s = 0; s < 10; ++s) {
    const int m0 = m_base + s * 32;
    const bf16x8 kf0 = *(const bf16x8*)&Kb[(size_t)(b * 5440 + m0 + lr) * 256 + head * 32 + g * 8];
    const bf16x8 kf1 = *(const bf16x8*)&Kb[(size_t)(b * 5440 + m0 + 16 + lr) * 256 + head * 32 + g * 8];
    const size_t vrow = ((size_t)(b * 8 + head) * 32 + lr) * 5440 + m0 + g * 8;
    const bf16x8 vf0 = *(const bf16x8*)&Vt[vrow];
    const bf16x8 vf1 = *(const bf16x8*)&Vt[vrow + 16 * 5440];
    const u16* bb = biasT + ((size_t)(b * 5440 + m0 + lr)) * 112 + g * 4;
#pragma unroll
    for (int mt = 0; mt < 7; ++mt) {
      f32x4 s0 = __builtin_amdgcn_mfma_f32_16x16x32_bf16(qf[mt], kf0, zf, 0, 0, 0);
      f32x4 s1 = __builtin_amdgcn_mfma_f32_16x16x32_bf16(qf[mt], kf1, zf, 0, 0, 0);
      const uint2 b0 = *(const uint2*)(bb + mt * 16);
      const uint2 b1 = *(const uint2*)(bb + 16 * 112 + mt * 16);
      s0[0] += b2f((u16)b0.x);      s0[1] += b2f((u16)(b0.x >> 16));
      s0[2] += b2f((u16)b0.y);      s0[3] += b2f((u16)(b0.y >> 16));
      s1[0] += b2f((u16)b1.x);      s1[1] += b2f((u16)(b1.x >> 16));
      s1[2] += b2f((u16)b1.y);      s1[3] += b2f((u16)(b1.y >> 16));
      float mx = fmaxf(fmaxf(fmaxf(s0[0], s0[1]), fmaxf(s0[2], s0[3])),
                       fmaxf(fmaxf(s1[0], s1[1]), fmaxf(s1[2], s1[3])));
#pragma unroll
      for (int d = 1; d < 16; d <<= 1) mx = fmaxf(mx, __shfl_xor(mx, d, 16));
      const float newM = fmaxf(Mst[mt], mx);
      const float al = __expf(Mst[mt] - newM);
      Mst[mt] = newM;
      f32x4 p0, p1;
#pragma unroll
      for (int r = 0; r < 4; ++r) {
        p0[r] = __expf(s0[r] - newM);
        p1[r] = __expf(s1[r] - newM);
      }
      Lp[mt] = Lp[mt] * al + (p0 + p1);
      Oa[mt][0] *= al;
      Oa[mt][1] *= al;
#pragma unroll
      for (int r = 0; r < 4; ++r)
        P32[wid][mt * 16 + g * 4 + r][lr] = (u32)f2b(p0[r]) | ((u32)f2b(p1[r]) << 16);
    }
#pragma unroll
    for (int mt = 0; mt < 7; ++mt) {
      const bf16x8 pa = *(const bf16x8*)&P32[wid][mt * 16 + lr][g * 4];
      Oa[mt][0] = __builtin_amdgcn_mfma_f32_16x16x32_bf16(pa, vf0, Oa[mt][0], 0, 0, 0);
      Oa[mt][1] = __builtin_amdgcn_mfma_f32_16x16x32_bf16(pa, vf1, Oa[mt][1], 0, 0, 0);
    }
  }
  const int bh = b * 8 + head;
#pragma unroll
  for (int mt = 0; mt < 7; ++mt)
#pragma unroll
    for (int r = 0; r < 4; ++r) {
      const int qr = mt * 16 + g * 4 + r;
      if (qr < 100) {
        float L = Lp[mt][r];
#pragma unroll
        for (int d = 1; d < 16; d <<= 1) L += __shfl_xor(L, d, 16);
        const size_t rb = (size_t)(bh * 17 + c) * 100 + qr;
        Opart[rb * 32 + lr] = Oa[mt][0][r];
        Opart[rb * 32 + 16 + lr] = Oa[mt][1][r];
        if (lr == 0) { ML[rb * 2] = Mst[mt]; ML[rb * 2 + 1] = L; }
      }
    }
}

// ---------------- Combine cross-attn partials -> attn_out bf16 [1600,256] ------
__global__ __launch_bounds__(256)
void reduce_attn_kernel(const float* __restrict__ Opart, const float* __restrict__ ML,
                        u16* __restrict__ outb)
{
  const int row = blockIdx.x;            // 0..1599
  const int b = row / 100, q = row % 100;
  const int h = threadIdx.x >> 5, d = threadIdx.x & 31;
  const int bh = b * 8 + h;
  float gm = -1e30f;
  for (int c = 0; c < 17; ++c) gm = fmaxf(gm, ML[((size_t)(bh * 17 + c) * 100 + q) * 2]);
  float l = 0.f, o = 0.f;
  for (int c = 0; c < 17; ++c) {
    const size_t rb = (size_t)(bh * 17 + c) * 100 + q;
    const float w = __expf(ML[rb * 2] - gm);
    l += ML[rb * 2 + 1] * w;
    o += Opart[rb * 32 + d] * w;
  }
  outb[(size_t)row * 256 + h * 32 + d] = f2b(o / l);
}

// ---------------- Self-attention (NQ=100, tiny) ----------------
__global__ __launch_bounds__(128)
void self_attn_kernel(const float* __restrict__ qk, const float* __restrict__ vs,
                      u16* __restrict__ so)
{
  __shared__ u16 kk[100][36];
  __shared__ u16 vv[100][36];
  __shared__ float S[100][101];
  const int b = blockIdx.x >> 3, h = blockIdx.x & 7;
  const int t = threadIdx.x;
  for (int e = t; e < 3200; e += 128) {
    const int r = e >> 5, cq = e & 31;
    kk[r][cq] = f2b(qk[(size_t)(b * 100 + r) * 512 + 256 + h * 32 + cq]);
    vv[r][cq] = f2b(vs[(size_t)(b * 100 + r) * 256 + h * 32 + cq]);
  }
  __syncthreads();
  if (t < 100) {
    float qr_[32];
#pragma unroll
    for (int cq = 0; cq < 32; ++cq) qr_[cq] = qk[(size_t)(b * 100 + t) * 512 + h * 32 + cq];
    for (int m = 0; m < 100; ++m) {
      float dp = 0.f;
#pragma unroll
      for (int cq = 0; cq < 32; ++cq) dp += qr_[cq] * b2f(kk[m][cq]);
      S[t][m] = dp * 0.17677669529663687f;
    }
    float mx = -1e30f;
    for (int m = 0; m < 100; ++m) mx = fmaxf(mx, S[t][m]);
    float sum = 0.f;
    for (int m = 0; m < 100; ++m) { const float p = __expf(S[t][m] - mx); S[t][m] = p; sum += p; }
    const float inv = 1.f / sum;
    float o[32];
#pragma unroll
    for (int cq = 0; cq < 32; ++cq) o[cq] = 0.f;
    for (int m = 0; m < 100; ++m) {
      const float p = S[t][m];
#pragma unroll
      for (int cq = 0; cq < 32; ++cq) o[cq] += p * b2f(vv[m][cq]);
    }
#pragma unroll
    for (int cq = 0; cq < 32; ++cq)
      so[(size_t)(b * 100 + t) * 256 + h * 32 + cq] = f2b(o[cq] * inv);
  }
}

// ---------------- mask_logits: per-b [100,256] @ hr[b][4096,256]^T (hr fp32 inline-cvt)
__global__ __launch_bounds__(256)
void mask_gemm_kernel(const u16* __restrict__ tm, const float* __restrict__ hr,
                      float* __restrict__ out)
{
  __shared__ u16 As[112][40];
  __shared__ u16 Bs[64][40];
  const int tid = threadIdx.x, lane = tid & 63, wid = tid >> 6;
  const int g = lane >> 4, lr = lane & 15;
  const int b = blockIdx.y, n0 = blockIdx.x * 64;
  f32x4 acc[7] = {};
  for (int k0 = 0; k0 < 256; k0 += 32) {
    for (int cid = tid; cid < 448; cid += 256) {
      const int r = cid >> 2, cg = (cid & 3) * 8;
      uint4 val = {0u, 0u, 0u, 0u};
      if (r < 100) val = *(const uint4*)&tm[(size_t)(b * 100 + r) * 256 + k0 + cg];
      *(uint4*)&As[r][cg] = val;
    }
    {
      const int r = tid >> 2, cg = (tid & 3) * 8;
      const float* hp = hr + (size_t)(b * 4096 + n0 + r) * 256 + k0 + cg;
      float4 f0 = *(const float4*)hp;
      float4 f1 = *(const float4*)(hp + 4);
      uint4 pk;
      pk.x = (u32)f2b(f0.x) | ((u32)f2b(f0.y) << 16);
      pk.y = (u32)f2b(f0.z) | ((u32)f2b(f0.w) << 16);
      pk.z = (u32)f2b(f1.x) | ((u32)f2b(f1.y) << 16);
      pk.w = (u32)f2b(f1.z) | ((u32)f2b(f1.w) << 16);
      *(uint4*)&Bs[r][cg] = pk;
    }
    __syncthreads();
    const bf16x8 bfr = *(const bf16x8*)&Bs[wid * 16 + lr][g * 8];
#pragma unroll
    for (int mt = 0; mt < 7; ++mt) {
      const bf16x8 af = *(const bf16x8*)&As[mt * 16 + lr][g * 8];
      acc[mt] = __builtin_amdgcn_mfma_f32_16x16x32_bf16(af, bfr, acc[mt], 0, 0, 0);
    }
    __syncthreads();
  }
#pragma unroll
  for (int mt = 0; mt < 7; ++mt)
#pragma unroll
    for (int r = 0; r < 4; ++r) {
      const int qr = mt * 16 + g * 4 + r;
      if (qr < 100)
        out[(size_t)(b * 100 + qr) * 4096 + n0 + wid * 16 + lr] = acc[mt][r];
    }
}

// =======================================================================
extern "C" void kernel_launch(void* const* d_in, const int* in_sizes, int n_in,
                              void* d_out, int out_size, void* d_ws, size_t ws_size,
                              hipStream_t stream)
{
  (void)in_sizes; (void)n_in; (void)out_size; (void)ws_size;
  const float* tgt      = (const float*)d_in[0];
  const float* memory   = (const float*)d_in[1];
  const float* memhr    = (const float*)d_in[2];
  const float* pbias    = (const float*)d_in[3];
  const float* qpos     = (const float*)d_in[4];
  const float* lncw     = (const float*)d_in[5];
  const float* lncb     = (const float*)d_in[6];
  const float* q_w      = (const float*)d_in[7];
  const float* q_b      = (const float*)d_in[8];
  const float* k_w      = (const float*)d_in[9];
  const float* k_b      = (const float*)d_in[10];
  const float* v_w      = (const float*)d_in[11];
  const float* v_b      = (const float*)d_in[12];
  const float* out_w    = (const float*)d_in[13];
  const float* out_b    = (const float*)d_in[14];
  const float* lnsw     = (const float*)d_in[15];
  const float* lnsb     = (const float*)d_in[16];
  const float* sa_in_w  = (const float*)d_in[17];
  const float* sa_in_b  = (const float*)d_in[18];
  const float* sa_out_w = (const float*)d_in[19];
  const float* sa_out_b = (const float*)d_in[20];
  const float* lnfw     = (const float*)d_in[21];
  const float* lnfb     = (const float*)d_in[22];
  const float* l1w      = (const float*)d_in[23];
  const float* l1b      = (const float*)d_in[24];
  const float* l2w      = (const float*)d_in[25];
  const float* l2b      = (const float*)d_in[26];
  const float* me_w     = (const float*)d_in[27];
  const float* me_b     = (const float*)d_in[28];
  float* outf = (float*)d_out;

  char* ws = (char*)d_ws;
  size_t off = 0;
  auto alloc = [&](size_t bytes) -> void* {
    void* p = ws + off;
    off = (off + bytes + 255) & ~(size_t)255;
    return p;
  };
  u16*   kvW   = (u16*)alloc((size_t)131072 * 2);
  u16*   qW    = (u16*)alloc((size_t)65536 * 2);
  u16*   outW  = (u16*)alloc((size_t)65536 * 2);
  u16*   saW   = (u16*)alloc((size_t)196608 * 2);
  u16*   saoW  = (u16*)alloc((size_t)65536 * 2);
  u16*   l1W   = (u16*)alloc((size_t)524288 * 2);
  u16*   l2W   = (u16*)alloc((size_t)524288 * 2);
  u16*   meW   = (u16*)alloc((size_t)65536 * 2);
  float* kvB   = (float*)alloc((size_t)512 * 4);
  u16*   biasT = (u16*)alloc((size_t)9748480 * 2);
  u16*   zq1   = (u16*)alloc((size_t)409600 * 2);
  u16*   Qb    = (u16*)alloc((size_t)409600 * 2);
  u16*   Kb    = (u16*)alloc((size_t)22282240 * 2);
  u16*   Vt    = (u16*)alloc((size_t)22282240 * 2);
  float* Opart = (float*)alloc((size_t)6963200 * 4);
  float* MLp   = (float*)alloc((size_t)435200 * 4);
  u16*   attno = (u16*)alloc((size_t)409600 * 2);
  float* tgt1  = (float*)alloc((size_t)409600 * 4);
  u16*   z2    = (u16*)alloc((size_t)409600 * 2);
  u16*   zq2   = (u16*)alloc((size_t)409600 * 2);
  float* qkb   = (float*)alloc((size_t)819200 * 4);
  float* vsb   = (float*)alloc((size_t)409600 * 4);
  u16*   sob   = (u16*)alloc((size_t)409600 * 2);
  float* tgt2  = (float*)alloc((size_t)409600 * 4);
  u16*   y0b   = (u16*)alloc((size_t)409600 * 2);
  u16*   hb    = (u16*)alloc((size_t)3276800 * 2);
  u16*   t3b   = (u16*)alloc((size_t)409600 * 2);
  u16*   tmb   = (u16*)alloc((size_t)409600 * 2);

  const float SCALE = 0.17677669529663687f;  // 32^-0.5

  // fused weight conversions (one launch) + kv bias pack
  Segs segs;
  segs.s[0] = {k_w,      kvW,          16384};
  segs.s[1] = {v_w,      kvW + 65536,  16384};
  segs.s[2] = {q_w,      qW,           16384};
  segs.s[3] = {out_w,    outW,         16384};
  segs.s[4] = {sa_in_w,  saW,          49152};
  segs.s[5] = {sa_out_w, saoW,         16384};
  segs.s[6] = {l1w,      l1W,          131072};
  segs.s[7] = {l2w,      l2W,          131072};
  segs.s[8] = {me_w,     meW,          16384};
  f2b_multi_kernel<<<dim3(512, 9), 256, 0, stream>>>(segs);
  copy_bias_kernel<<<1, 512, 0, stream>>>(k_b, v_b, kvB);
  bias_tr_kernel<<<dim3(85, 16), 256, 0, stream>>>(pbias, biasT);

  // ---- cross attention ----
  ln_kernel<<<400, 256, 0, stream>>>(tgt, lncw, lncb, qpos, nullptr, zq1);
  gemm_kernel<16, 128, 1, 4, 0, 0, 0, 0, 1><<<dim3(100, 2), 256, 0, stream>>>(
      zq1, qW, q_b, nullptr, nullptr, Qb, 1600, 256, 256, SCALE);
  kv_gemm_kernel<<<dim3(1360), 512, 0, stream>>>(memory, kvW, kvW + 65536, kvB, Kb, Vt);
  cross_attn_kernel<<<dim3(17, 16, 2), 256, 0, stream>>>(Qb, Kb, Vt, biasT, Opart, MLp);
  reduce_attn_kernel<<<1600, 256, 0, stream>>>(Opart, MLp, attno);
  gemm_kernel<16, 128, 1, 4, 0, 0, 1, 1, 0><<<dim3(100, 2), 256, 0, stream>>>(
      attno, outW, out_b, tgt, tgt1, nullptr, 1600, 256, 256, 1.f);

  // ---- self attention ----
  ln_kernel<<<400, 256, 0, stream>>>(tgt1, lnsw, lnsb, qpos, z2, zq2);
  gemm_kernel<16, 128, 1, 4, 0, 0, 0, 1, 0><<<dim3(100, 4), 256, 0, stream>>>(
      zq2, saW, sa_in_b, nullptr, qkb, nullptr, 1600, 512, 256, 1.f);
  gemm_kernel<16, 128, 1, 4, 0, 0, 0, 1, 0><<<dim3(100, 2), 256, 0, stream>>>(
      z2, saW + 131072, sa_in_b + 512, nullptr, vsb, nullptr, 1600, 256, 256, 1.f);
  self_attn_kernel<<<128, 128, 0, stream>>>(qkb, vsb, sob);
  gemm_kernel<16, 128, 1, 4, 0, 0, 1, 1, 0><<<dim3(100, 2), 256, 0, stream>>>(
      sob, saoW, sa_out_b, tgt1, tgt2, nullptr, 1600, 256, 256, 1.f);

  // ---- FFN ----
  ln_kernel<<<400, 256, 0, stream>>>(tgt2, lnfw, lnfb, nullptr, y0b, nullptr);
  gemm_kernel<64, 256, 4, 1, 0, 1, 0, 0, 1><<<dim3(25, 8), 256, 0, stream>>>(
      y0b, l1W, l1b, nullptr, nullptr, hb, 1600, 2048, 256, 1.f);
  gemm_kernel<16, 128, 1, 4, 0, 0, 1, 1, 1><<<dim3(100, 2), 256, 0, stream>>>(
      hb, l2W, l2b, tgt2, outf, t3b, 1600, 256, 2048, 1.f);

  // ---- mask branch ----
  gemm_kernel<16, 128, 1, 4, 0, 0, 0, 0, 1><<<dim3(100, 2), 256, 0, stream>>>(
      t3b, meW, me_b, nullptr, nullptr, tmb, 1600, 256, 256, 1.f);
  mask_gemm_kernel<<<dim3(64, 16), 256, 0, stream>>>(tmb, memhr, outf + 409600);
}

// Round 5
// 339.514 us; speedup vs baseline: 1.4820x; 1.0918x over previous
//
#include <hip/hip_runtime.h>

typedef unsigned short u16;
typedef unsigned int u32;
typedef __bf16 bf16x8 __attribute__((ext_vector_type(8)));
typedef float f32x4 __attribute__((ext_vector_type(4)));

__device__ __forceinline__ u16 f2b(float f) {
  u32 u = __float_as_uint(f);
  u32 r = (u + 0x7fffu + ((u >> 16) & 1u)) >> 16;   // RNE, inputs finite
  return (u16)r;
}
__device__ __forceinline__ float b2f(u16 h) {
  return __uint_as_float(((u32)h) << 16);
}
__device__ __forceinline__ bf16x8 zero8() {
  union { uint4 u; bf16x8 v; } z; z.u = make_uint4(0u, 0u, 0u, 0u); return z.v;
}
__device__ __forceinline__ u32 cvtpk(float lo, float hi) {
  u32 r;
  asm("v_cvt_pk_bf16_f32 %0, %1, %2" : "=v"(r) : "v"(lo), "v"(hi));
  return r;
}

// ================= PREP: weight cvt + Wf pack + bias pack + bias transpose ====
struct Seg { const float* in; u16* out; int n4; };
struct PrepArgs {
  Seg seg[7];
  const float *k_w, *v_w, *k_b, *v_b, *pbias;
  u16 *Wf, *biasT;
  float *kvB;
};

// grid: [0,1472) f2b segs | [1472,1536) Wf pack | [1536,1538) kv bias | [1538,2898) bias_tr
__global__ __launch_bounds__(256)
void prep_kernel(PrepArgs a)
{
  __shared__ float S[100][69];
  const int bx = blockIdx.x, tid = threadIdx.x;
  if (bx < 1472) {
    int bxr = bx;
#pragma unroll
    for (int k = 0; k < 7; ++k) {
      const int nb = a.seg[k].n4 >> 8;
      if (bxr < nb) {
        const int i = bxr * 256 + tid;
        const float4 f = *(const float4*)(a.seg[k].in + (size_t)i * 4);
        uint2 pk; pk.x = cvtpk(f.x, f.y); pk.y = cvtpk(f.z, f.w);
        *(uint2*)(a.seg[k].out + (size_t)i * 4) = pk;
        return;
      }
      bxr -= nb;
    }
    return;
  } else if (bx < 1536) {
    // fragment-major pack: Wf[((gI*8+ks)*4+nt)*512 + lane*8 + j]
    //   = W[gI*64 + nt*16 + (lane&15)][ks*32 + (lane>>4)*8 + j], W = [k_w;v_w]
    const int i = bx - 1472, gI = i >> 3, ks = i & 7;
    const int nt = tid >> 6, lane = tid & 63, lr = lane & 15, g = lane >> 4;
    const float* src = (gI < 4 ? a.k_w + (size_t)(gI * 64 + nt * 16 + lr) * 256
                               : a.v_w + (size_t)((gI - 4) * 64 + nt * 16 + lr) * 256)
                       + ks * 32 + g * 8;
    const float4 f0 = *(const float4*)src;
    const float4 f1 = *(const float4*)(src + 4);
    uint4 pk;
    pk.x = cvtpk(f0.x, f0.y); pk.y = cvtpk(f0.z, f0.w);
    pk.z = cvtpk(f1.x, f1.y); pk.w = cvtpk(f1.z, f1.w);
    *(uint4*)(a.Wf + (size_t)((gI * 8 + ks) * 4 + nt) * 512 + lane * 8) = pk;
  } else if (bx < 1538) {
    const int i = (bx - 1536) * 256 + tid;
    a.kvB[i] = (i < 256) ? a.k_b[i] : a.v_b[i - 256];
  } else {
    // bias transpose: pbias[b][100 q][5440 m] f32 -> biasT[b][m][112 q] bf16
    const int bt = bx - 1538;
    const int b = bt / 85, m0 = (bt - b * 85) * 64;
    for (int idx = tid; idx < 1600; idx += 256) {
      const int q = idx >> 4, seg = idx & 15;
      const float4 v = *(const float4*)(a.pbias + (size_t)(b * 100 + q) * 5440 + m0 + seg * 4);
      S[q][seg * 4 + 0] = v.x; S[q][seg * 4 + 1] = v.y;
      S[q][seg * 4 + 2] = v.z; S[q][seg * 4 + 3] = v.w;
    }
    __syncthreads();
    for (int idx = tid; idx < 1792; idx += 256) {
      const int m = idx / 28, qg = (idx % 28) * 4;
      u16 h[4];
#pragma unroll
      for (int r = 0; r < 4; ++r) {
        const int q = qg + r;
        h[r] = (q < 100) ? f2b(S[q][m]) : (u16)0;
      }
      uint2 pk;
      pk.x = (u32)h[0] | ((u32)h[1] << 16);
      pk.y = (u32)h[2] | ((u32)h[3] << 16);
      *(uint2*)(a.biasT + ((size_t)(b * 5440 + m0 + m)) * 112 + qg) = pk;
    }
  }
}

// ---------------- LN staging into swizzled bf16 LDS tile [ROWS][256] ----------
template<int ROWS>
__device__ __forceinline__ void ln_stage(const float* __restrict__ x, int row0,
    const float* __restrict__ w, const float* __restrict__ b,
    const float* __restrict__ pos, u16* As)
{
  const int tid = threadIdx.x, lane = tid & 63, wid = tid >> 6;
  const float4 wv = *(const float4*)(w + lane * 4);
  const float4 bv = *(const float4*)(b + lane * 4);
#pragma unroll
  for (int rr = 0; rr < ROWS / 4; ++rr) {
    const int rl = wid * (ROWS / 4) + rr;
    const size_t o = (size_t)(row0 + rl) * 256 + lane * 4;
    const float4 v = *(const float4*)(x + o);
    float s = v.x + v.y + v.z + v.w;
#pragma unroll
    for (int m = 1; m < 64; m <<= 1) s += __shfl_xor(s, m);
    const float mean = s * (1.f / 256.f);
    const float d0 = v.x - mean, d1 = v.y - mean, d2 = v.z - mean, d3 = v.w - mean;
    float ss = d0 * d0 + d1 * d1 + d2 * d2 + d3 * d3;
#pragma unroll
    for (int m = 1; m < 64; m <<= 1) ss += __shfl_xor(ss, m);
    const float rs = rsqrtf(ss * (1.f / 256.f) + 1e-5f);
    float y0 = d0 * rs * wv.x + bv.x;
    float y1 = d1 * rs * wv.y + bv.y;
    float y2 = d2 * rs * wv.z + bv.z;
    float y3 = d3 * rs * wv.w + bv.w;
    if (pos) {
      const float4 pv = *(const float4*)(pos + o);
      y0 += pv.x; y1 += pv.y; y2 += pv.z; y3 += pv.w;
    }
    uint2 pk; pk.x = cvtpk(y0, y1); pk.y = cvtpk(y2, y3);
    const int byte = (rl * 512 + lane * 8) ^ ((rl & 7) << 4);
    *(uint2*)((char*)As + byte) = pk;
  }
}

// 16x128 GEMM loop reading A from full-K swizzled LDS; W staged per k0.
__device__ __forceinline__ void gemm16x128(const u16* As, const u16* __restrict__ W,
                                           u16 (*Ws)[40], f32x4 acc[2])
{
  const int tid = threadIdx.x, lane = tid & 63, wid = tid >> 6;
  const int g = lane >> 4, lr = lane & 15;
  for (int k0 = 0; k0 < 256; k0 += 32) {
    for (int cid = tid; cid < 512; cid += 256) {
      const int r = cid >> 2, cg = (cid & 3) * 8;
      *(uint4*)&Ws[r][cg] = *(const uint4*)(W + (size_t)r * 256 + k0 + cg);
    }
    __syncthreads();
    const int abyte = (lr * 512 + k0 * 2 + g * 16) ^ ((lr & 7) << 4);
    const bf16x8 af = *(const bf16x8*)((const char*)As + abyte);
#pragma unroll
    for (int nt = 0; nt < 2; ++nt) {
      const bf16x8 bfr = *(const bf16x8*)&Ws[wid * 32 + nt * 16 + lr][g * 8];
      acc[nt] = __builtin_amdgcn_mfma_f32_16x16x32_bf16(af, bfr, acc[nt], 0, 0, 0);
    }
    __syncthreads();
  }
}

// ---------------- q-proj fused with LN(tgt)+qpos; out bf16 scaled -------------
__global__ __launch_bounds__(256)
void qproj_kernel(const float* __restrict__ x, const float* __restrict__ lnw,
                  const float* __restrict__ lnb, const float* __restrict__ pos,
                  const u16* __restrict__ W, const float* __restrict__ bias,
                  u16* __restrict__ out, float scale)
{
  __shared__ u16 As[16 * 256];
  __shared__ u16 Ws[128][40];
  const int tid = threadIdx.x, lane = tid & 63, wid = tid >> 6;
  const int g = lane >> 4, lr = lane & 15;
  const int row0 = blockIdx.x * 16, n0 = blockIdx.y * 128;
  ln_stage<16>(x, row0, lnw, lnb, pos, As);
  f32x4 acc[2] = {};
  gemm16x128(As, W + (size_t)n0 * 256, Ws, acc);
#pragma unroll
  for (int nt = 0; nt < 2; ++nt) {
    const int col = n0 + wid * 32 + nt * 16 + lr;
    const float bv = bias[col];
#pragma unroll
    for (int r = 0; r < 4; ++r) {
      const int row = row0 + g * 4 + r;
      out[(size_t)row * 256 + col] = f2b((acc[nt][r] + bv) * scale);
    }
  }
}

// ---------------- sa_in fused: LN(tgt1)(+qpos for qk), N=768 ------------------
__global__ __launch_bounds__(256)
void sain_kernel(const float* __restrict__ x, const float* __restrict__ lnw,
                 const float* __restrict__ lnb, const float* __restrict__ pos,
                 const u16* __restrict__ W, const float* __restrict__ bias,
                 float* __restrict__ qkb, float* __restrict__ vsb)
{
  __shared__ u16 As[16 * 256];
  __shared__ u16 Ws[128][40];
  const int tid = threadIdx.x, lane = tid & 63, wid = tid >> 6;
  const int g = lane >> 4, lr = lane & 15;
  const int row0 = blockIdx.x * 16, y = blockIdx.y;
  ln_stage<16>(x, row0, lnw, lnb, (y < 4) ? pos : nullptr, As);
  f32x4 acc[2] = {};
  gemm16x128(As, W + (size_t)y * 128 * 256, Ws, acc);
#pragma unroll
  for (int nt = 0; nt < 2; ++nt) {
    const int cl = wid * 32 + nt * 16 + lr;
    const float bv = bias[y * 128 + cl];
#pragma unroll
    for (int r = 0; r < 4; ++r) {
      const int row = row0 + g * 4 + r;
      const float v = acc[nt][r] + bv;
      if (y < 4) qkb[(size_t)row * 512 + y * 128 + cl] = v;
      else       vsb[(size_t)row * 256 + (y - 4) * 128 + cl] = v;
    }
  }
}

// ---------------- FFN lin1 fused with LN(tgt2); GELU; out bf16 ---------------
__global__ __launch_bounds__(256)
void ffn1_kernel(const float* __restrict__ x, const float* __restrict__ lnw,
                 const float* __restrict__ lnb, const u16* __restrict__ W,
                 const float* __restrict__ bias, u16* __restrict__ out)
{
  __shared__ u16 As[64 * 256];
  __shared__ u16 Ws[256][40];
  const int tid = threadIdx.x, lane = tid & 63, wid = tid >> 6;
  const int g = lane >> 4, lr = lane & 15;
  const int row0 = blockIdx.x * 64, n0 = blockIdx.y * 256;
  ln_stage<64>(x, row0, lnw, lnb, nullptr, As);
  f32x4 acc[16] = {};
  for (int k0 = 0; k0 < 256; k0 += 32) {
    for (int cid = tid; cid < 1024; cid += 256) {
      const int r = cid >> 2, cg = (cid & 3) * 8;
      *(uint4*)&Ws[r][cg] = *(const uint4*)(W + (size_t)(n0 + r) * 256 + k0 + cg);
    }
    __syncthreads();
    const int arow = wid * 16 + lr;
    const int abyte = (arow * 512 + k0 * 2 + g * 16) ^ ((arow & 7) << 4);
    const bf16x8 af = *(const bf16x8*)((const char*)As + abyte);
#pragma unroll
    for (int nt = 0; nt < 16; ++nt) {
      const bf16x8 bfr = *(const bf16x8*)&Ws[nt * 16 + lr][g * 8];
      acc[nt] = __builtin_amdgcn_mfma_f32_16x16x32_bf16(af, bfr, acc[nt], 0, 0, 0);
    }
    __syncthreads();
  }
#pragma unroll
  for (int nt = 0; nt < 16; ++nt) {
    const int col = n0 + nt * 16 + lr;
    const float bv = bias[col];
#pragma unroll
    for (int r = 0; r < 4; ++r) {
      const int row = row0 + wid * 16 + g * 4 + r;
      float v = acc[nt][r] + bv;
      v = 0.5f * v * (1.f + erff(v * 0.70710678118654752f));
      out[(size_t)row * 2048 + col] = f2b(v);
    }
  }
}

// ---------------- Generic GEMM: C[M,N] = A[M,K] @ W[N,K]^T + bias -------------
template<int BM, int BN, int WM, int WN, int GELU_, int RES_, int OF32, int OBF>
__global__ __launch_bounds__(256)
void gemm_kernel(const u16* __restrict__ Ap, const u16* __restrict__ W,
                 const float* __restrict__ bias, const float* __restrict__ res,
                 float* __restrict__ Cf, u16* __restrict__ Cb,
                 int M, int N, int K, float scale)
{
  constexpr int WROWS = BM / WM;
  constexpr int WCOLS = BN / WN;
  constexpr int MT = WROWS / 16;
  constexpr int NT = WCOLS / 16;
  static_assert(WM * WN == 4, "4 waves");
  __shared__ u16 As[BM][40];
  __shared__ u16 Ws[BN][40];
  const int tid = threadIdx.x, lane = tid & 63, wid = tid >> 6;
  const int g = lane >> 4, lr = lane & 15;
  const int m0 = blockIdx.x * BM, n0 = blockIdx.y * BN;
  const int wm = wid / WN, wn = wid % WN;
  f32x4 acc[MT][NT] = {};
  for (int k0 = 0; k0 < K; k0 += 32) {
    for (int cid = tid; cid < BM * 4; cid += 256) {
      int r = cid >> 2, cg = (cid & 3) * 8;
      *(uint4*)&As[r][cg] = *(const uint4*)(Ap + (size_t)(m0 + r) * K + k0 + cg);
    }
    for (int cid = tid; cid < BN * 4; cid += 256) {
      int r = cid >> 2, cg = (cid & 3) * 8;
      *(uint4*)&Ws[r][cg] = *(const uint4*)(W + (size_t)(n0 + r) * K + k0 + cg);
    }
    __syncthreads();
    bf16x8 af[MT], bfr[NT];
#pragma unroll
    for (int mt = 0; mt < MT; ++mt) af[mt] = *(const bf16x8*)&As[wm * WROWS + mt * 16 + lr][g * 8];
#pragma unroll
    for (int nt = 0; nt < NT; ++nt) bfr[nt] = *(const bf16x8*)&Ws[wn * WCOLS + nt * 16 + lr][g * 8];
#pragma unroll
    for (int mt = 0; mt < MT; ++mt)
#pragma unroll
      for (int nt = 0; nt < NT; ++nt)
        acc[mt][nt] = __builtin_amdgcn_mfma_f32_16x16x32_bf16(af[mt], bfr[nt], acc[mt][nt], 0, 0, 0);
    __syncthreads();
  }
#pragma unroll
  for (int mt = 0; mt < MT; ++mt)
#pragma unroll
    for (int nt = 0; nt < NT; ++nt) {
      const int col = n0 + wn * WCOLS + nt * 16 + lr;
      const float bv = bias[col];
#pragma unroll
      for (int r = 0; r < 4; ++r) {
        const int row = m0 + wm * WROWS + mt * 16 + g * 4 + r;
        float v = (acc[mt][nt][r] + bv) * scale;
        if constexpr (GELU_) v = 0.5f * v * (1.f + erff(v * 0.70710678118654752f));
        if constexpr (RES_) v += res[(size_t)row * N + col];
        if constexpr (OF32) Cf[(size_t)row * N + col] = v;
        if constexpr (OBF) Cb[(size_t)row * N + col] = f2b(v);
      }
    }
}

// ---------------- KV projection GEMM — coalesced Wf + LDS-assembled stores ----
// 1360 blocks x 512 thr; block = 64 rows x 512 cols (K 0-255 | V 256-511).
// A staged bf16 in LDS full-K (32 KB swizzled, 1 barrier); W via fragment-major
// Wf (1 KB contiguous per wave-load). Epilogues assembled in LDS (reuse As) and
// stored with 16B/lane coalesced bursts.
__global__ __launch_bounds__(512, 4)
void kv_gemm_kernel(const float* __restrict__ A, const u16* __restrict__ Wf,
                    const float* __restrict__ biasKV,
                    u16* __restrict__ Kb, u16* __restrict__ Vt)
{
  __shared__ u16 As[64 * 256];
  const int tid = threadIdx.x, lane = tid & 63, wid = tid >> 6;
  const int g = lane >> 4, lr = lane & 15;
  const int bidx = blockIdx.x / 85, t = blockIdx.x - bidx * 85;
  const int row0 = blockIdx.x * 64;

  // ---- stage A tile (64 x 256) fp32 -> bf16, swizzled ----
  for (int ch = tid; ch < 2048; ch += 512) {
    const int r = ch >> 5, c8 = (ch & 31) * 8;
    const float* ap = A + (size_t)(row0 + r) * 256 + c8;
    const float4 f0 = *(const float4*)ap;
    const float4 f1 = *(const float4*)(ap + 4);
    uint4 pk;
    pk.x = cvtpk(f0.x, f0.y);
    pk.y = cvtpk(f0.z, f0.w);
    pk.z = cvtpk(f1.x, f1.y);
    pk.w = cvtpk(f1.z, f1.w);
    const int byte = r * 512 + c8 * 2;
    *(uint4*)((char*)As + (byte ^ ((r & 7) << 4))) = pk;
  }
  __syncthreads();

  const u16* wbase = Wf + (size_t)wid * 8 * 4 * 512 + lane * 8;
  f32x4 acc[4][4] = {};
#pragma unroll 2
  for (int ks = 0; ks < 8; ++ks) {
    bf16x8 bfv[4], af[4];
#pragma unroll
    for (int nt = 0; nt < 4; ++nt)
      bfv[nt] = *(const bf16x8*)(wbase + (ks * 4 + nt) * 512);
#pragma unroll
    for (int mt = 0; mt < 4; ++mt) {
      const int r = mt * 16 + lr;
      const int byte = r * 512 + ks * 64 + g * 16;
      af[mt] = *(const bf16x8*)((const char*)As + (byte ^ ((r & 7) << 4)));
    }
#pragma unroll
    for (int mt = 0; mt < 4; ++mt)
#pragma unroll
      for (int nt = 0; nt < 4; ++nt)
        acc[mt][nt] = __builtin_amdgcn_mfma_f32_16x16x32_bf16(af[mt], bfv[nt], acc[mt][nt], 0, 0, 0);
  }
  __syncthreads();   // all As reads done

  const int isV = wid >> 2;
  // ---- V assembly: LDSv[col 0..255][slot 0..63], byte ^= (col&7)<<4 ----
  if (isV) {
#pragma unroll
    for (int nt = 0; nt < 4; ++nt) {
      const int col = (wid - 4) * 64 + nt * 16 + lr;
      const float bv = biasKV[256 + col];
#pragma unroll
      for (int mt = 0; mt < 4; ++mt)
#pragma unroll
        for (int r = 0; r < 4; ++r) {
          const int slot = (mt >> 1) * 32 + 8 * g + 2 * r + (mt & 1);  // permuted
          const int byte = (col * 128 + slot * 2) ^ ((col & 7) << 4);
          *(u16*)((char*)As + byte) = f2b(acc[mt][nt][r] + bv);
        }
    }
  }
  __syncthreads();
  // ---- coop V store: row = bidx*256+col, 128B per row ----
  {
    const size_t vbase = (size_t)bidx * 256 * 5440 + (size_t)t * 64;
#pragma unroll
    for (int p = 0; p < 4; ++p) {
      const int idx = p * 512 + tid;
      const int col = idx >> 3, chunk = idx & 7;
      const int lbyte = col * 128 + ((chunk * 16) ^ ((col & 7) << 4));
      const uint4 v = *(const uint4*)((const char*)As + lbyte);
      *(uint4*)(Vt + vbase + (size_t)col * 5440 + chunk * 8) = v;
    }
  }
  __syncthreads();   // coop V reads done
  // ---- K assembly: LDSk[row 0..63][col 0..255], byte ^= (row&7)<<4 ----
  if (!isV) {
#pragma unroll
    for (int nt = 0; nt < 4; ++nt) {
      const int col = wid * 64 + nt * 16 + lr;
      const float bv = biasKV[col];
#pragma unroll
      for (int mt = 0; mt < 4; ++mt)
#pragma unroll
        for (int r = 0; r < 4; ++r) {
          const int row = mt * 16 + g * 4 + r;
          const int byte = (row * 512 + col * 2) ^ ((row & 7) << 4);
          *(u16*)((char*)As + byte) = f2b(acc[mt][nt][r] + bv);
        }
    }
  }
  __syncthreads();
  // ---- coop K store: 512B per row ----
#pragma unroll
  for (int p = 0; p < 4; ++p) {
    const int idx = p * 512 + tid;
    const int row = idx >> 5, c16 = idx & 31;
    const int lbyte = row * 512 + ((c16 * 16) ^ ((row & 7) << 4));
    const uint4 v = *(const uint4*)((const char*)As + lbyte);
    *(uint4*)(Kb + (size_t)(row0 + row) * 256 + c16 * 8) = v;
  }
}

// ---------------- Cross-attention, flash split-K over NM ----------------
__global__ __launch_bounds__(256, 3)
void cross_attn_kernel(const u16* __restrict__ Q, const u16* __restrict__ Kb,
                       const u16* __restrict__ Vt, const u16* __restrict__ biasT,
                       float* __restrict__ Opart, float* __restrict__ ML)
{
  __shared__ u32 P32[4][112][20];
  const int tid = threadIdx.x, lane = tid & 63, wid = tid >> 6;
  const int g = lane >> 4, lr = lane & 15;
  const int b = blockIdx.y, c = blockIdx.x;
  const int head = blockIdx.z * 4 + wid;
  const int m_base = c * 320;
  const f32x4 zf = {0.f, 0.f, 0.f, 0.f};

  bf16x8 qf[7];
#pragma unroll
  for (int mt = 0; mt < 7; ++mt) {
    int qr = mt * 16 + lr;
    qf[mt] = (qr < 100) ? *(const bf16x8*)&Q[(size_t)(b * 100 + qr) * 256 + head * 32 + g * 8]
                        : zero8();
  }
  float Mst[7];
  f32x4 Lp[7];
  f32x4 Oa[7][2];
#pragma unroll
  for (int mt = 0; mt < 7; ++mt) { Mst[mt] = -1e30f; Lp[mt] = zf; Oa[mt][0] = zf; Oa[mt][1] = zf; }

  for (int s = 0; s < 10; ++s) {
    const int m0 = m_base + s * 32;
    const bf16x8 kf0 = *(const bf16x8*)&Kb[(size_t)(b * 5440 + m0 + lr) * 256 + head * 32 + g * 8];
    const bf16x8 kf1 = *(const bf16x8*)&Kb[(size_t)(b * 5440 + m0 + 16 + lr) * 256 + head * 32 + g * 8];
    const size_t vrow = ((size_t)(b * 8 + head) * 32 + lr) * 5440 + m0 + g * 8;
    const bf16x8 vf0 = *(const bf16x8*)&Vt[vrow];
    const bf16x8 vf1 = *(const bf16x8*)&Vt[vrow + 16 * 5440];
    const u16* bb = biasT + ((size_t)(b * 5440 + m0 + lr)) * 112 + g * 4;
#pragma unroll
    for (int mt = 0; mt < 7; ++mt) {
      f32x4 s0 = __builtin_amdgcn_mfma_f32_16x16x32_bf16(qf[mt], kf0, zf, 0, 0, 0);
      f32x4 s1 = __builtin_amdgcn_mfma_f32_16x16x32_bf16(qf[mt], kf1, zf, 0, 0, 0);
      const uint2 b0 = *(const uint2*)(bb + mt * 16);
      const uint2 b1 = *(const uint2*)(bb + 16 * 112 + mt * 16);
      s0[0] += b2f((u16)b0.x);      s0[1] += b2f((u16)(b0.x >> 16));
      s0[2] += b2f((u16)b0.y);      s0[3] += b2f((u16)(b0.y >> 16));
      s1[0] += b2f((u16)b1.x);      s1[1] += b2f((u16)(b1.x >> 16));
      s1[2] += b2f((u16)b1.y);      s1[3] += b2f((u16)(b1.y >> 16));
      float mx = fmaxf(fmaxf(fmaxf(s0[0], s0[1]), fmaxf(s0[2], s0[3])),
                       fmaxf(fmaxf(s1[0], s1[1]), fmaxf(s1[2], s1[3])));
#pragma unroll
      for (int d = 1; d < 16; d <<= 1) mx = fmaxf(mx, __shfl_xor(mx, d, 16));
      const float newM = fmaxf(Mst[mt], mx);
      const float al = __expf(Mst[mt] - newM);
      Mst[mt] = newM;
      f32x4 p0, p1;
#pragma unroll
      for (int r = 0; r < 4; ++r) {
        p0[r] = __expf(s0[r] - newM);
        p1[r] = __expf(s1[r] - newM);
      }
      Lp[mt] = Lp[mt] * al + (p0 + p1);
      Oa[mt][0] *= al;
      Oa[mt][1] *= al;
#pragma unroll
      for (int r = 0; r < 4; ++r)
        P32[wid][mt * 16 + g * 4 + r][lr] = (u32)f2b(p0[r]) | ((u32)f2b(p1[r]) << 16);
    }
#pragma unroll
    for (int mt = 0; mt < 7; ++mt) {
      const bf16x8 pa = *(const bf16x8*)&P32[wid][mt * 16 + lr][g * 4];
      Oa[mt][0] = __builtin_amdgcn_mfma_f32_16x16x32_bf16(pa, vf0, Oa[mt][0], 0, 0, 0);
      Oa[mt][1] = __builtin_amdgcn_mfma_f32_16x16x32_bf16(pa, vf1, Oa[mt][1], 0, 0, 0);
    }
  }
  const int bh = b * 8 + head;
#pragma unroll
  for (int mt = 0; mt < 7; ++mt)
#pragma unroll
    for (int r = 0; r < 4; ++r) {
      const int qr = mt * 16 + g * 4 + r;
      if (qr < 100) {
        float L = Lp[mt][r];
#pragma unroll
        for (int d = 1; d < 16; d <<= 1) L += __shfl_xor(L, d, 16);
        const size_t rb = (size_t)(bh * 17 + c) * 100 + qr;
        Opart[rb * 32 + lr] = Oa[mt][0][r];
        Opart[rb * 32 + 16 + lr] = Oa[mt][1][r];
        if (lr == 0) { ML[rb * 2] = Mst[mt]; ML[rb * 2 + 1] = L; }
      }
    }
}

// ---------------- Combine cross-attn partials -> attn_out bf16 [1600,256] ------
__global__ __launch_bounds__(256)
void reduce_attn_kernel(const float* __restrict__ Opart, const float* __restrict__ ML,
                        u16* __restrict__ outb)
{
  const int row = blockIdx.x;            // 0..1599
  const int b = row / 100, q = row % 100;
  const int h = threadIdx.x >> 5, d = threadIdx.x & 31;
  const int bh = b * 8 + h;
  float gm = -1e30f;
  for (int c = 0; c < 17; ++c) gm = fmaxf(gm, ML[((size_t)(bh * 17 + c) * 100 + q) * 2]);
  float l = 0.f, o = 0.f;
  for (int c = 0; c < 17; ++c) {
    const size_t rb = (size_t)(bh * 17 + c) * 100 + q;
    const float w = __expf(ML[rb * 2] - gm);
    l += ML[rb * 2 + 1] * w;
    o += Opart[rb * 32 + d] * w;
  }
  outb[(size_t)row * 256 + h * 32 + d] = f2b(o / l);
}

// ---------------- Self-attention (NQ=100, tiny) ----------------
__global__ __launch_bounds__(128)
void self_attn_kernel(const float* __restrict__ qk, const float* __restrict__ vs,
                      u16* __restrict__ so)
{
  __shared__ u16 kk[100][36];
  __shared__ u16 vv[100][36];
  __shared__ float S[100][101];
  const int b = blockIdx.x >> 3, h = blockIdx.x & 7;
  const int t = threadIdx.x;
  for (int e = t; e < 3200; e += 128) {
    const int r = e >> 5, cq = e & 31;
    kk[r][cq] = f2b(qk[(size_t)(b * 100 + r) * 512 + 256 + h * 32 + cq]);
    vv[r][cq] = f2b(vs[(size_t)(b * 100 + r) * 256 + h * 32 + cq]);
  }
  __syncthreads();
  if (t < 100) {
    float qr_[32];
#pragma unroll
    for (int cq = 0; cq < 32; ++cq) qr_[cq] = qk[(size_t)(b * 100 + t) * 512 + h * 32 + cq];
    for (int m = 0; m < 100; ++m) {
      float dp = 0.f;
#pragma unroll
      for (int cq = 0; cq < 32; ++cq) dp += qr_[cq] * b2f(kk[m][cq]);
      S[t][m] = dp * 0.17677669529663687f;
    }
    float mx = -1e30f;
    for (int m = 0; m < 100; ++m) mx = fmaxf(mx, S[t][m]);
    float sum = 0.f;
    for (int m = 0; m < 100; ++m) { const float p = __expf(S[t][m] - mx); S[t][m] = p; sum += p; }
    const float inv = 1.f / sum;
    float o[32];
#pragma unroll
    for (int cq = 0; cq < 32; ++cq) o[cq] = 0.f;
    for (int m = 0; m < 100; ++m) {
      const float p = S[t][m];
#pragma unroll
      for (int cq = 0; cq < 32; ++cq) o[cq] += p * b2f(vv[m][cq]);
    }
#pragma unroll
    for (int cq = 0; cq < 32; ++cq)
      so[(size_t)(b * 100 + t) * 256 + h * 32 + cq] = f2b(o[cq] * inv);
  }
}

// ---------------- mask_logits: per-b [100,256] @ hr[b][4096,256]^T -------------
__global__ __launch_bounds__(256)
void mask_gemm_kernel(const u16* __restrict__ tm, const float* __restrict__ hr,
                      float* __restrict__ out)
{
  __shared__ u16 As[112][40];
  __shared__ u16 Bs[64][40];
  const int tid = threadIdx.x, lane = tid & 63, wid = tid >> 6;
  const int g = lane >> 4, lr = lane & 15;
  const int b = blockIdx.y, n0 = blockIdx.x * 64;
  f32x4 acc[7] = {};
  for (int k0 = 0; k0 < 256; k0 += 32) {
    for (int cid = tid; cid < 448; cid += 256) {
      const int r = cid >> 2, cg = (cid & 3) * 8;
      uint4 val = {0u, 0u, 0u, 0u};
      if (r < 100) val = *(const uint4*)&tm[(size_t)(b * 100 + r) * 256 + k0 + cg];
      *(uint4*)&As[r][cg] = val;
    }
    {
      const int r = tid >> 2, cg = (tid & 3) * 8;
      const float* hp = hr + (size_t)(b * 4096 + n0 + r) * 256 + k0 + cg;
      float4 f0 = *(const float4*)hp;
      float4 f1 = *(const float4*)(hp + 4);
      uint4 pk;
      pk.x = cvtpk(f0.x, f0.y); pk.y = cvtpk(f0.z, f0.w);
      pk.z = cvtpk(f1.x, f1.y); pk.w = cvtpk(f1.z, f1.w);
      *(uint4*)&Bs[r][cg] = pk;
    }
    __syncthreads();
    const bf16x8 bfr = *(const bf16x8*)&Bs[wid * 16 + lr][g * 8];
#pragma unroll
    for (int mt = 0; mt < 7; ++mt) {
      const bf16x8 af = *(const bf16x8*)&As[mt * 16 + lr][g * 8];
      acc[mt] = __builtin_amdgcn_mfma_f32_16x16x32_bf16(af, bfr, acc[mt], 0, 0, 0);
    }
    __syncthreads();
  }
#pragma unroll
  for (int mt = 0; mt < 7; ++mt)
#pragma unroll
    for (int r = 0; r < 4; ++r) {
      const int qr = mt * 16 + g * 4 + r;
      if (qr < 100)
        out[(size_t)(b * 100 + qr) * 4096 + n0 + wid * 16 + lr] = acc[mt][r];
    }
}

// =======================================================================
extern "C" void kernel_launch(void* const* d_in, const int* in_sizes, int n_in,
                              void* d_out, int out_size, void* d_ws, size_t ws_size,
                              hipStream_t stream)
{
  (void)in_sizes; (void)n_in; (void)out_size; (void)ws_size;
  const float* tgt      = (const float*)d_in[0];
  const float* memory   = (const float*)d_in[1];
  const float* memhr    = (const float*)d_in[2];
  const float* pbias    = (const float*)d_in[3];
  const float* qpos     = (const float*)d_in[4];
  const float* lncw     = (const float*)d_in[5];
  const float* lncb     = (const float*)d_in[6];
  const float* q_w      = (const float*)d_in[7];
  const float* q_b      = (const float*)d_in[8];
  const float* k_w      = (const float*)d_in[9];
  const float* k_b      = (const float*)d_in[10];
  const float* v_w      = (const float*)d_in[11];
  const float* v_b      = (const float*)d_in[12];
  const float* out_w    = (const float*)d_in[13];
  const float* out_b    = (const float*)d_in[14];
  const float* lnsw     = (const float*)d_in[15];
  const float* lnsb     = (const float*)d_in[16];
  const float* sa_in_w  = (const float*)d_in[17];
  const float* sa_in_b  = (const float*)d_in[18];
  const float* sa_out_w = (const float*)d_in[19];
  const float* sa_out_b = (const float*)d_in[20];
  const float* lnfw     = (const float*)d_in[21];
  const float* lnfb     = (const float*)d_in[22];
  const float* l1w      = (const float*)d_in[23];
  const float* l1b      = (const float*)d_in[24];
  const float* l2w      = (const float*)d_in[25];
  const float* l2b      = (const float*)d_in[26];
  const float* me_w     = (const float*)d_in[27];
  const float* me_b     = (const float*)d_in[28];
  float* outf = (float*)d_out;

  char* ws = (char*)d_ws;
  size_t off = 0;
  auto alloc = [&](size_t bytes) -> void* {
    void* p = ws + off;
    off = (off + bytes + 255) & ~(size_t)255;
    return p;
  };
  u16*   Wf    = (u16*)alloc((size_t)131072 * 2);   // fragment-major [k_w;v_w]
  u16*   qW    = (u16*)alloc((size_t)65536 * 2);
  u16*   outW  = (u16*)alloc((size_t)65536 * 2);
  u16*   saW   = (u16*)alloc((size_t)196608 * 2);
  u16*   saoW  = (u16*)alloc((size_t)65536 * 2);
  u16*   l1W   = (u16*)alloc((size_t)524288 * 2);
  u16*   l2W   = (u16*)alloc((size_t)524288 * 2);
  u16*   meW   = (u16*)alloc((size_t)65536 * 2);
  float* kvB   = (float*)alloc((size_t)512 * 4);
  u16*   biasT = (u16*)alloc((size_t)9748480 * 2);
  u16*   Qb    = (u16*)alloc((size_t)409600 * 2);
  u16*   Kb    = (u16*)alloc((size_t)22282240 * 2);
  u16*   Vt    = (u16*)alloc((size_t)22282240 * 2);
  float* Opart = (float*)alloc((size_t)6963200 * 4);
  float* MLp   = (float*)alloc((size_t)435200 * 4);
  u16*   attno = (u16*)alloc((size_t)409600 * 2);
  float* tgt1  = (float*)alloc((size_t)409600 * 4);
  float* qkb   = (float*)alloc((size_t)819200 * 4);
  float* vsb   = (float*)alloc((size_t)409600 * 4);
  u16*   sob   = (u16*)alloc((size_t)409600 * 2);
  float* tgt2  = (float*)alloc((size_t)409600 * 4);
  u16*   hb    = (u16*)alloc((size_t)3276800 * 2);
  u16*   t3b   = (u16*)alloc((size_t)409600 * 2);
  u16*   tmb   = (u16*)alloc((size_t)409600 * 2);

  const float SCALE = 0.17677669529663687f;  // 32^-0.5

  // ---- single prep launch ----
  PrepArgs pa;
  pa.seg[0] = {q_w,      qW,   16384};
  pa.seg[1] = {out_w,    outW, 16384};
  pa.seg[2] = {sa_in_w,  saW,  49152};
  pa.seg[3] = {sa_out_w, saoW, 16384};
  pa.seg[4] = {l1w,      l1W,  131072};
  pa.seg[5] = {l2w,      l2W,  131072};
  pa.seg[6] = {me_w,     meW,  16384};
  pa.k_w = k_w; pa.v_w = v_w; pa.k_b = k_b; pa.v_b = v_b; pa.pbias = pbias;
  pa.Wf = Wf; pa.biasT = biasT; pa.kvB = kvB;
  prep_kernel<<<2898, 256, 0, stream>>>(pa);

  // ---- cross attention ----
  qproj_kernel<<<dim3(100, 2), 256, 0, stream>>>(tgt, lncw, lncb, qpos, qW, q_b, Qb, SCALE);
  kv_gemm_kernel<<<dim3(1360), 512, 0, stream>>>(memory, Wf, kvB, Kb, Vt);
  cross_attn_kernel<<<dim3(17, 16, 2), 256, 0, stream>>>(Qb, Kb, Vt, biasT, Opart, MLp);
  reduce_attn_kernel<<<1600, 256, 0, stream>>>(Opart, MLp, attno);
  gemm_kernel<16, 128, 1, 4, 0, 1, 1, 0><<<dim3(100, 2), 256, 0, stream>>>(
      attno, outW, out_b, tgt, tgt1, nullptr, 1600, 256, 256, 1.f);

  // ---- self attention ----
  sain_kernel<<<dim3(100, 6), 256, 0, stream>>>(tgt1, lnsw, lnsb, qpos, saW, sa_in_b, qkb, vsb);
  self_attn_kernel<<<128, 128, 0, stream>>>(qkb, vsb, sob);
  gemm_kernel<16, 128, 1, 4, 0, 1, 1, 0><<<dim3(100, 2), 256, 0, stream>>>(
      sob, saoW, sa_out_b, tgt1, tgt2, nullptr, 1600, 256, 256, 1.f);

  // ---- FFN ----
  ffn1_kernel<<<dim3(25, 8), 256, 0, stream>>>(tgt2, lnfw, lnfb, l1W, l1b, hb);
  gemm_kernel<16, 128, 1, 4, 0, 1, 1, 1><<<dim3(100, 2), 256, 0, stream>>>(
      hb, l2W, l2b, tgt2, outf, t3b, 1600, 256, 2048, 1.f);

  // ---- mask branch ----
  gemm_kernel<16, 128, 1, 4, 0, 0, 0, 1><<<dim3(100, 2), 256, 0, stream>>>(
      t3b, meW, me_b, nullptr, nullptr, tmb, 1600, 256, 256, 1.f);
  mask_gemm_kernel<<<dim3(64, 16), 256, 0, stream>>>(tmb, memhr, outf + 409600);
}